// Round 14
// baseline (271.636 us; speedup 1.0000x reference)
//
#include <hip/hip_runtime.h>
#include <math.h>

// Sizes: B=8, L=1024, D=512, N=64, NC=4, HIDDEN=1024, up rows=2048, R=64

typedef short bf16x8 __attribute__((ext_vector_type(8)));
typedef float f32x4 __attribute__((ext_vector_type(4)));

__device__ __forceinline__ float fast_sigmoid(float x) { return 1.0f / (1.0f + __expf(-x)); }
__device__ __forceinline__ float fast_gelu(float x) {
    float u = 0.7978845608f * (x + 0.044715f * x * x * x);
    float t = 1.0f - 2.0f / (1.0f + __expf(2.0f * u));
    return 0.5f * x * (1.0f + t);
}
__device__ __forceinline__ unsigned short f2bf(float f) {
    unsigned u = __float_as_uint(f);
    unsigned r = (u + 0x7FFFu + ((u >> 16) & 1u)) >> 16;
    return (unsigned short)r;
}
__device__ __forceinline__ unsigned pk2(unsigned short a, unsigned short b) {
    return (unsigned)a | ((unsigned)b << 16);
}

// ---------------------------------------------------------------------------
// front_kernel: prep_comp + compute_bbar + convert_all + transpose_x fused
// by block range (unchanged from R13).
// ---------------------------------------------------------------------------
__global__ __launch_bounds__(256) void front_kernel(const float* __restrict__ log_dt,
                                                    const float* __restrict__ Bp,
                                                    const float* __restrict__ up_w,
                                                    const float* __restrict__ dn_w,
                                                    const float* __restrict__ Cp,
                                                    const float* __restrict__ x,
                                                    float* __restrict__ Pow,
                                                    unsigned short* __restrict__ Bb_h,
                                                    unsigned short* __restrict__ Bb_l,
                                                    unsigned short* __restrict__ up_wb,
                                                    unsigned short* __restrict__ dn_wb,
                                                    unsigned short* __restrict__ Cp_h,
                                                    unsigned short* __restrict__ Cp_l,
                                                    float* __restrict__ xT) {
    __shared__ __align__(16) float smem[16640];
    int bid = blockIdx.x, tid = threadIdx.x;
    if (bid < 4) {
        float* M1 = smem;
        float* M1T = smem + 4096;
        float* M2 = smem + 8192;
        float* M2T = smem + 12288;
        int comp = bid;
        float ldt = log_dt[comp];
        float dt = log1pf(expf(ldt)) + 1e-6f;
        float hdt = 0.5f * dt;
        if (tid < 64) {
            int j = tid;
            float sqj = sqrtf(2.0f * (float)j + 1.0f);
            float S = 0.0f;
            for (int i = 0; i < 64; ++i) {
                float sqi = sqrtf(2.0f * (float)i + 1.0f);
                float r = (i == j) ? (1.0f - hdt * (float)(i + 1))
                                   : ((i > j) ? (-hdt * sqi * sqj) : 0.0f);
                float X = (r - hdt * sqi * S) / (1.0f + hdt * (float)(i + 1));
                M1[i * 64 + j] = X;
                M1T[j * 64 + i] = X;
                S += sqi * X;
            }
        }
        __syncthreads();
        for (int ii = tid; ii < 4096; ii += 256) Pow[(size_t)comp * 40960 + ii] = M1[ii];
        float* cur = M1; float* curT = M1T; float* nxt = M2; float* nxtT = M2T;
        int ti = tid >> 4, tj = tid & 15;
        for (int s = 1; s <= 9; ++s) {
            float c[4][4] = {{0}};
#pragma unroll 8
            for (int k = 0; k < 64; ++k) {
                float4 a = *(const float4*)&curT[k * 64 + ti * 4];
                float4 b = *(const float4*)&cur[k * 64 + tj * 4];
                c[0][0] += a.x * b.x; c[0][1] += a.x * b.y; c[0][2] += a.x * b.z; c[0][3] += a.x * b.w;
                c[1][0] += a.y * b.x; c[1][1] += a.y * b.y; c[1][2] += a.y * b.z; c[1][3] += a.y * b.w;
                c[2][0] += a.z * b.x; c[2][1] += a.z * b.y; c[2][2] += a.z * b.z; c[2][3] += a.z * b.w;
                c[3][0] += a.w * b.x; c[3][1] += a.w * b.y; c[3][2] += a.w * b.z; c[3][3] += a.w * b.w;
            }
#pragma unroll
            for (int r = 0; r < 4; ++r) {
                float4 row; row.x = c[r][0]; row.y = c[r][1]; row.z = c[r][2]; row.w = c[r][3];
                *(float4*)&nxt[(ti * 4 + r) * 64 + tj * 4] = row;
                float4 colv; colv.x = c[0][r]; colv.y = c[1][r]; colv.z = c[2][r]; colv.w = c[3][r];
                *(float4*)&nxtT[(tj * 4 + r) * 64 + ti * 4] = colv;
            }
            __syncthreads();
            for (int ii = tid; ii < 4096; ii += 256) Pow[(size_t)comp * 40960 + s * 4096 + ii] = nxt[ii];
            float* t0 = cur; cur = nxt; nxt = t0;
            float* t1 = curT; curT = nxtT; nxtT = t1;
            __syncthreads();
        }
    } else if (bid < 12) {
        int gid = (bid - 4) * 256 + tid;
        int comp = gid >> 9;
        float ldt = log_dt[comp];
        float dt = log1pf(expf(ldt)) + 1e-6f;
        float hdt = 0.5f * dt;
        const float* bp = Bp + (size_t)gid * 64;
        unsigned short* oh = Bb_h + (size_t)gid * 64;
        unsigned short* ol = Bb_l + (size_t)gid * 64;
        float S = 0.0f;
        for (int i = 0; i < 64; ++i) {
            float sqi = sqrtf(2.0f * (float)i + 1.0f);
            float y = (dt * bp[i] - hdt * sqi * S) / (1.0f + hdt * (float)(i + 1));
            unsigned short h = f2bf(y);
            oh[i] = h;
            ol[i] = f2bf(y - __uint_as_float((unsigned)h << 16));
            S += sqi * y;
        }
    } else if (bid < 844) {
        int i = (bid - 12) * 256 + tid;
        if (i < 196608) {
            const float* src = (i < 131072) ? up_w : dn_w;
            unsigned short* dst = (i < 131072) ? up_wb : dn_wb;
            int j = (i < 131072) ? i : (i - 131072);
            float4 a = ((const float4*)src)[2 * j];
            float4 b = ((const float4*)src)[2 * j + 1];
            uint4 o;
            o.x = pk2(f2bf(a.x), f2bf(a.y));
            o.y = pk2(f2bf(a.z), f2bf(a.w));
            o.z = pk2(f2bf(b.x), f2bf(b.y));
            o.w = pk2(f2bf(b.z), f2bf(b.w));
            *(uint4*)&dst[(size_t)j * 8] = o;
        } else if (i < 212992) {
            int j = i - 196608;
            float4 a = ((const float4*)Cp)[2 * j];
            float4 b = ((const float4*)Cp)[2 * j + 1];
            float vv[8] = {a.x, a.y, a.z, a.w, b.x, b.y, b.z, b.w};
            unsigned short hs[8], ls[8];
#pragma unroll
            for (int k = 0; k < 8; ++k) {
                unsigned short h = f2bf(vv[k]);
                hs[k] = h;
                ls[k] = f2bf(vv[k] - __uint_as_float((unsigned)h << 16));
            }
            uint4 ho, lo;
            ho.x = pk2(hs[0], hs[1]); ho.y = pk2(hs[2], hs[3]); ho.z = pk2(hs[4], hs[5]); ho.w = pk2(hs[6], hs[7]);
            lo.x = pk2(ls[0], ls[1]); lo.y = pk2(ls[2], ls[3]); lo.z = pk2(ls[4], ls[5]); lo.w = pk2(ls[6], ls[7]);
            *(uint4*)&Cp_h[(size_t)j * 8] = ho;
            *(uint4*)&Cp_l[(size_t)j * 8] = lo;
        }
    } else {
        int li = bid - 844;
        int bx = li & 31, by = (li >> 5) & 15, bz = li >> 9;
        float* tile = smem;
        int r0 = bx * 32, c0 = by * 32, b = bz;
        int tx = tid & 31, ty = tid >> 5;
#pragma unroll
        for (int m = 0; m < 4; ++m)
            tile[(ty + 8 * m) * 33 + tx] = x[((size_t)b * 1024 + r0 + ty + 8 * m) * 512 + c0 + tx];
        __syncthreads();
#pragma unroll
        for (int m = 0; m < 4; ++m)
            xT[((size_t)b * 512 + c0 + ty + 8 * m) * 1024 + r0 + tx] = tile[tx * 33 + ty + 8 * m];
    }
}

// ---------------------------------------------------------------------------
// power_mats: unchanged.
// ---------------------------------------------------------------------------
__global__ __launch_bounds__(256) void power_mats(const float* __restrict__ Pow,
                                                  unsigned short* __restrict__ Pst_h,
                                                  unsigned short* __restrict__ Pst_l,
                                                  unsigned short* __restrict__ Qst_h,
                                                  unsigned short* __restrict__ Qst_l) {
    int idx = blockIdx.x, comp = blockIdx.y, tid = threadIdx.x;
    __shared__ __align__(16) float R[4096], RT[4096], R2[4096], R2T[4096], SbT[4096];
    int isP = (idx < 32) ? 1 : 0;
    int f = isP ? idx : (idx - 32);
    int base_s = isP ? 0 : 5;
    const float* PowC = Pow + (size_t)comp * 40960;
    int i_ = tid & 63, kc = (tid >> 6) * 16;
    float* cur = R; float* curT = RT; float* nx = R2; float* nxT = R2T;
    if (f == 0) {
        for (int ii = tid; ii < 4096; ii += 256) {
            float v = ((ii >> 6) == (ii & 63)) ? 1.0f : 0.0f;
            R[ii] = v; RT[ii] = v;
        }
        __syncthreads();
    } else {
        int b0 = __ffs(f) - 1;
        const float* S0 = PowC + (size_t)(base_s + b0) * 4096;
#pragma unroll
        for (int j = 0; j < 16; j += 4) {
            float4 v = *(const float4*)&S0[i_ * 64 + kc + j];
            *(float4*)&R[i_ * 64 + kc + j] = v;
            RT[(kc + j + 0) * 64 + i_] = v.x;
            RT[(kc + j + 1) * 64 + i_] = v.y;
            RT[(kc + j + 2) * 64 + i_] = v.z;
            RT[(kc + j + 3) * 64 + i_] = v.w;
        }
        int rem = f & ~(1 << b0);
        int ti = tid >> 4, tj = tid & 15;
        __syncthreads();
        while (rem) {
            int b = __ffs(rem) - 1; rem &= rem - 1;
            const float* Sb = PowC + (size_t)(base_s + b) * 4096;
#pragma unroll
            for (int j = 0; j < 16; j += 4) {
                float4 v = *(const float4*)&Sb[i_ * 64 + kc + j];
                SbT[(kc + j + 0) * 64 + i_] = v.x;
                SbT[(kc + j + 1) * 64 + i_] = v.y;
                SbT[(kc + j + 2) * 64 + i_] = v.z;
                SbT[(kc + j + 3) * 64 + i_] = v.w;
            }
            __syncthreads();
            float c[4][4] = {{0}};
#pragma unroll 8
            for (int k = 0; k < 64; ++k) {
                float4 a = *(const float4*)&SbT[k * 64 + ti * 4];
                float4 b4 = *(const float4*)&cur[k * 64 + tj * 4];
                c[0][0] += a.x * b4.x; c[0][1] += a.x * b4.y; c[0][2] += a.x * b4.z; c[0][3] += a.x * b4.w;
                c[1][0] += a.y * b4.x; c[1][1] += a.y * b4.y; c[1][2] += a.y * b4.z; c[1][3] += a.y * b4.w;
                c[2][0] += a.z * b4.x; c[2][1] += a.z * b4.y; c[2][2] += a.z * b4.z; c[2][3] += a.z * b4.w;
                c[3][0] += a.w * b4.x; c[3][1] += a.w * b4.y; c[3][2] += a.w * b4.z; c[3][3] += a.w * b4.w;
            }
#pragma unroll
            for (int r = 0; r < 4; ++r) {
                float4 row; row.x = c[r][0]; row.y = c[r][1]; row.z = c[r][2]; row.w = c[r][3];
                *(float4*)&nx[(ti * 4 + r) * 64 + tj * 4] = row;
                float4 colv; colv.x = c[0][r]; colv.y = c[1][r]; colv.z = c[2][r]; colv.w = c[3][r];
                *(float4*)&nxT[(tj * 4 + r) * 64 + ti * 4] = colv;
            }
            __syncthreads();
            float* t0 = cur; cur = nx; nx = t0;
            float* t1 = curT; curT = nxT; nxT = t1;
        }
    }
    const float* src = isP ? cur : curT;
    int outrow = isP ? idx : (idx - 32);
    unsigned short* dh = (isP ? Pst_h : Qst_h) + (size_t)comp * 131072 + (size_t)outrow * 4096;
    unsigned short* dl = (isP ? Pst_l : Qst_l) + (size_t)comp * 131072 + (size_t)outrow * 4096;
    for (int ii = tid * 8; ii < 4096; ii += 2048) {
        float4 v0 = *(const float4*)&src[ii];
        float4 v1 = *(const float4*)&src[ii + 4];
        float vv[8] = {v0.x, v0.y, v0.z, v0.w, v1.x, v1.y, v1.z, v1.w};
        unsigned short hs[8], ls[8];
#pragma unroll
        for (int j = 0; j < 8; ++j) {
            unsigned short h = f2bf(vv[j]);
            hs[j] = h;
            ls[j] = f2bf(vv[j] - __uint_as_float((unsigned)h << 16));
        }
        uint4 ho, lo;
        ho.x = pk2(hs[0], hs[1]); ho.y = pk2(hs[2], hs[3]); ho.z = pk2(hs[4], hs[5]); ho.w = pk2(hs[6], hs[7]);
        lo.x = pk2(ls[0], ls[1]); lo.y = pk2(ls[2], ls[3]); lo.z = pk2(ls[4], ls[5]); lo.w = pk2(ls[6], ls[7]);
        *(uint4*)&dh[ii] = ho;
        *(uint4*)&dl[ii] = lo;
    }
}

// ---------------------------------------------------------------------------
// kgemm_uv2: merged U and V (unchanged).
// ---------------------------------------------------------------------------
__global__ __launch_bounds__(256) void kgemm_uv2(const unsigned short* __restrict__ Bb_h,
                                                 const unsigned short* __restrict__ Bb_l,
                                                 const unsigned short* __restrict__ Pst_h,
                                                 const unsigned short* __restrict__ Pst_l,
                                                 const unsigned short* __restrict__ Cp_h,
                                                 const unsigned short* __restrict__ Cp_l,
                                                 const unsigned short* __restrict__ Qst_h,
                                                 const unsigned short* __restrict__ Qst_l,
                                                 unsigned short* __restrict__ V_h,
                                                 unsigned short* __restrict__ V_l,
                                                 unsigned short* __restrict__ U_h,
                                                 unsigned short* __restrict__ U_l) {
    int zz = blockIdx.z;
    int isV = (zz < 4) ? 1 : 0;
    int comp = isV ? zz : (zz - 4);
    const unsigned short* Ah = isV ? Bb_h : Cp_h;
    const unsigned short* Al = isV ? Bb_l : Cp_l;
    const unsigned short* Bh = isV ? Pst_h : Qst_h;
    const unsigned short* Bl = isV ? Pst_l : Qst_l;
    unsigned short* Ch = isV ? V_h : U_h;
    unsigned short* Cl = isV ? V_l : U_l;
    int m0 = blockIdx.x * 128, n0 = blockIdx.y * 64;
    int tid = threadIdx.x, w = tid >> 6, l = tid & 63;
    __shared__ __align__(16) short Ash[8192], Asl[8192], Bsh[4096], Bsl[4096];
    const unsigned short* Abh = Ah + (size_t)comp * 32768;
    const unsigned short* Abl = Al + (size_t)comp * 32768;
    const unsigned short* Bbh = Bh + (size_t)comp * 131072;
    const unsigned short* Bbl = Bl + (size_t)comp * 131072;
#pragma unroll
    for (int i = 0; i < 4; ++i) {
        int cid = tid + 256 * i;
        int row = cid >> 3, slot = cid & 7;
        int goff = (m0 + row) * 64 + slot * 8;
        int loff = row * 64 + (slot ^ (row & 7)) * 8;
        *(uint4*)&Ash[loff] = *(const uint4*)(Abh + goff);
        *(uint4*)&Asl[loff] = *(const uint4*)(Abl + goff);
    }
#pragma unroll
    for (int i = 0; i < 2; ++i) {
        int cid = tid + 256 * i;
        int row = cid >> 3, slot = cid & 7;
        int goff = (n0 + row) * 64 + slot * 8;
        int loff = row * 64 + (slot ^ (row & 7)) * 8;
        *(uint4*)&Bsh[loff] = *(const uint4*)(Bbh + goff);
        *(uint4*)&Bsl[loff] = *(const uint4*)(Bbl + goff);
    }
    __syncthreads();
    int p = l >> 4, lr = l & 15;
    f32x4 acc[2][4];
#pragma unroll
    for (int rt = 0; rt < 2; ++rt)
#pragma unroll
        for (int ct = 0; ct < 4; ++ct) acc[rt][ct] = (f32x4)0.0f;
#pragma unroll
    for (int ks = 0; ks < 2; ++ks) {
        bf16x8 ah2[2], al2[2], bh2[4], bl2[4];
#pragma unroll
        for (int rt = 0; rt < 2; ++rt) {
            int row = w * 32 + rt * 16 + lr;
            int off = row * 64 + ((ks * 4 + p) ^ (row & 7)) * 8;
            ah2[rt] = *(bf16x8*)&Ash[off];
            al2[rt] = *(bf16x8*)&Asl[off];
        }
#pragma unroll
        for (int ct = 0; ct < 4; ++ct) {
            int cr = ct * 16 + lr;
            int off = cr * 64 + ((ks * 4 + p) ^ (cr & 7)) * 8;
            bh2[ct] = *(bf16x8*)&Bsh[off];
            bl2[ct] = *(bf16x8*)&Bsl[off];
        }
#pragma unroll
        for (int rt = 0; rt < 2; ++rt)
#pragma unroll
            for (int ct = 0; ct < 4; ++ct) {
                acc[rt][ct] = __builtin_amdgcn_mfma_f32_16x16x32_bf16(ah2[rt], bh2[ct], acc[rt][ct], 0, 0, 0);
                acc[rt][ct] = __builtin_amdgcn_mfma_f32_16x16x32_bf16(ah2[rt], bl2[ct], acc[rt][ct], 0, 0, 0);
                acc[rt][ct] = __builtin_amdgcn_mfma_f32_16x16x32_bf16(al2[rt], bh2[ct], acc[rt][ct], 0, 0, 0);
            }
    }
#pragma unroll
    for (int rt = 0; rt < 2; ++rt)
#pragma unroll
        for (int ct = 0; ct < 4; ++ct) {
#pragma unroll
            for (int reg = 0; reg < 4; ++reg) {
                int row = m0 + w * 32 + rt * 16 + p * 4 + reg;
                int col = n0 + ct * 16 + lr;
                float v = acc[rt][ct][reg];
                unsigned short h = f2bf(v);
                unsigned short lo2 = f2bf(v - __uint_as_float((unsigned)h << 16));
                size_t o = (size_t)comp * 1048576 + (size_t)row * 2048 + col;
                Ch[o] = h;
                Cl[o] = lo2;
            }
        }
}

// ---------------------------------------------------------------------------
// kgemm_kr: fused kgemm_k + reduce_K (unchanged).
// ---------------------------------------------------------------------------
__global__ __launch_bounds__(256) void kgemm_kr(const unsigned short* __restrict__ Uh,
                                                const unsigned short* __restrict__ Ul,
                                                const unsigned short* __restrict__ Vh,
                                                const unsigned short* __restrict__ Vl,
                                                const float* __restrict__ Dp,
                                                float* __restrict__ Kr) {
    int tid = threadIdx.x, w = tid >> 6, l = tid & 63;
    int d = blockIdx.x;
    int g = w * 512 + d;
    int p = l >> 4, lr = l & 15;
    __shared__ float ksh[4096];
    const unsigned short* ubh = Uh + (size_t)g * 2048;
    const unsigned short* ubl = Ul + (size_t)g * 2048;
    const unsigned short* vbh = Vh + (size_t)g * 2048;
    const unsigned short* vbl = Vl + (size_t)g * 2048;
    f32x4 acc[2][2];
    acc[0][0] = (f32x4)0.0f; acc[0][1] = (f32x4)0.0f;
    acc[1][0] = (f32x4)0.0f; acc[1][1] = (f32x4)0.0f;
#pragma unroll
    for (int ks = 0; ks < 2; ++ks) {
        bf16x8 uh2[2], ul2[2], vh2[2], vl2[2];
#pragma unroll
        for (int mt = 0; mt < 2; ++mt) {
            int off = (mt * 16 + lr) * 64 + ks * 32 + p * 8;
            uh2[mt] = *(const bf16x8*)(ubh + off);
            ul2[mt] = *(const bf16x8*)(ubl + off);
            vh2[mt] = *(const bf16x8*)(vbh + off);
            vl2[mt] = *(const bf16x8*)(vbl + off);
        }
#pragma unroll
        for (int mt = 0; mt < 2; ++mt)
#pragma unroll
            for (int nt = 0; nt < 2; ++nt) {
                acc[mt][nt] = __builtin_amdgcn_mfma_f32_16x16x32_bf16(uh2[mt], vh2[nt], acc[mt][nt], 0, 0, 0);
                acc[mt][nt] = __builtin_amdgcn_mfma_f32_16x16x32_bf16(uh2[mt], vl2[nt], acc[mt][nt], 0, 0, 0);
                acc[mt][nt] = __builtin_amdgcn_mfma_f32_16x16x32_bf16(ul2[mt], vh2[nt], acc[mt][nt], 0, 0, 0);
            }
    }
#pragma unroll
    for (int mt = 0; mt < 2; ++mt)
#pragma unroll
        for (int nt = 0; nt < 2; ++nt)
#pragma unroll
            for (int reg = 0; reg < 4; ++reg) {
                int q = mt * 16 + p * 4 + reg;
                int r = nt * 16 + lr;
                ksh[w * 1024 + q * 32 + r] = acc[mt][nt][reg];
            }
    __syncthreads();
#pragma unroll
    for (int j = 0; j < 4; ++j) {
        int ll = tid * 4 + j;
        float s = ksh[ll] + ksh[1024 + ll] + ksh[2048 + ll] + ksh[3072 + ll];
        if (ll == 0) s += Dp[d] + Dp[512 + d] + Dp[1024 + d] + Dp[1536 + d];
        Kr[(size_t)d * 1024 + (1023 - ll)] = s;
    }
}

// ---------------------------------------------------------------------------
// MFMA depthwise conv (unchanged).
// ---------------------------------------------------------------------------
__global__ __launch_bounds__(256) void conv_mfma(const float* __restrict__ xT,
                                                 const float* __restrict__ Kr,
                                                 float* __restrict__ yT,
                                                 float* __restrict__ ssum) {
    int c = blockIdx.x, tid = threadIdx.x;
    int w = tid >> 6, l = tid & 63;
    __shared__ __align__(16) float krp[1088];
    __shared__ __align__(16) short xh[8512], xl[8512];
    __shared__ __align__(16) short gh[10240], gl[10240];
    __shared__ float ssh[64];

    {
        float4 kv = *(const float4*)&Kr[(size_t)c * 1024 + tid * 4];
        *(float4*)&krp[32 + tid * 4] = kv;
        if (tid < 8) *(float4*)&krp[tid * 4] = make_float4(0, 0, 0, 0);
        else if (tid < 16) *(float4*)&krp[1056 + (tid - 8) * 4] = make_float4(0, 0, 0, 0);
    }
    if (tid < 32) {
        int b = tid >> 2, g = tid & 3;
        uint4 z = {0, 0, 0, 0};
        *(uint4*)&xh[(b * 133 + g) * 8] = z;
    } else if (tid < 64) {
        int t2 = tid - 32; int b = t2 >> 2, g = t2 & 3;
        uint4 z = {0, 0, 0, 0};
        *(uint4*)&xl[(b * 133 + g) * 8] = z;
    }
#pragma unroll
    for (int i = 0; i < 4; ++i) {
        int gid = tid + 256 * i;
        int b = gid >> 7, gt = gid & 127;
        const float* src = &xT[((size_t)(b * 512 + c)) * 1024 + gt * 8];
        float4 v0 = *(const float4*)src;
        float4 v1 = *(const float4*)(src + 4);
        float vv[8] = {v0.x, v0.y, v0.z, v0.w, v1.x, v1.y, v1.z, v1.w};
        unsigned short hsv[8], lsv[8];
#pragma unroll
        for (int j2 = 0; j2 < 8; ++j2) {
            unsigned short h = f2bf(vv[j2]);
            hsv[j2] = h;
            lsv[j2] = f2bf(vv[j2] - __uint_as_float((unsigned)h << 16));
        }
        uint4 hh, ll;
        hh.x = pk2(hsv[0], hsv[1]); hh.y = pk2(hsv[2], hsv[3]);
        hh.z = pk2(hsv[4], hsv[5]); hh.w = pk2(hsv[6], hsv[7]);
        ll.x = pk2(lsv[0], lsv[1]); ll.y = pk2(lsv[2], lsv[3]);
        ll.z = pk2(lsv[4], lsv[5]); ll.w = pk2(lsv[6], lsv[7]);
        int off = (b * 133 + 4 + gt) * 8;
        *(uint4*)&xh[off] = hh;
        *(uint4*)&xl[off] = ll;
    }
    __syncthreads();

    f32x4 acc[4][2];
#pragma unroll
    for (int i = 0; i < 4; ++i) { acc[i][0] = (f32x4)0.0f; acc[i][1] = (f32x4)0.0f; }

    int lr = l & 15, kg4 = l >> 4;
    for (int ch = 0; ch < 4; ++ch) {
        int dq0 = ch * 8;
        {
            int dqloc = tid >> 5, n = tid & 31, dq = dq0 + dqloc;
            int s0 = 32 * dq + n + 1;
            int a0 = s0 & ~3, sh = s0 & 3;
            float ff[36];
#pragma unroll
            for (int i = 0; i < 9; ++i) *(float4*)&ff[i * 4] = *(const float4*)&krp[a0 + i * 4];
            unsigned short hsv[32], lsv[32];
#pragma unroll
            for (int k = 0; k < 32; ++k) {
                int j2 = 31 - k;
                float v = (sh == 0) ? ff[j2] : (sh == 1) ? ff[j2 + 1] : (sh == 2) ? ff[j2 + 2] : ff[j2 + 3];
                unsigned short h = f2bf(v);
                hsv[k] = h;
                lsv[k] = f2bf(v - __uint_as_float((unsigned)h << 16));
            }
            int gbase = (dqloc * 32 + n) * 5 * 8;
#pragma unroll
            for (int kg = 0; kg < 4; ++kg) {
                uint4 hh, ll;
                hh.x = pk2(hsv[8 * kg + 0], hsv[8 * kg + 1]);
                hh.y = pk2(hsv[8 * kg + 2], hsv[8 * kg + 3]);
                hh.z = pk2(hsv[8 * kg + 4], hsv[8 * kg + 5]);
                hh.w = pk2(hsv[8 * kg + 6], hsv[8 * kg + 7]);
                ll.x = pk2(lsv[8 * kg + 0], lsv[8 * kg + 1]);
                ll.y = pk2(lsv[8 * kg + 2], lsv[8 * kg + 3]);
                ll.z = pk2(lsv[8 * kg + 4], lsv[8 * kg + 5]);
                ll.w = pk2(lsv[8 * kg + 6], lsv[8 * kg + 7]);
                *(uint4*)&gh[gbase + kg * 8] = hh;
                *(uint4*)&gl[gbase + kg * 8] = ll;
            }
        }
        __syncthreads();
        for (int dqloc = 0; dqloc < 8; ++dqloc) {
            int dq = dq0 + dqloc;
            bf16x8 bh[2], bl[2];
#pragma unroll
            for (int nf = 0; nf < 2; ++nf) {
                int go = ((dqloc * 32 + nf * 16 + lr) * 5 + kg4) * 8;
                bh[nf] = *(bf16x8*)&gh[go];
                bl[nf] = *(bf16x8*)&gl[go];
            }
#pragma unroll
            for (int ffi = 0; ffi < 4; ++ffi) {
                int F = w + 4 * ffi;
                if (2 * F + 1 < dq) continue;
                int b = lr & 7, qoff = lr >> 3;
                int q = 2 * F + qoff;
                int j = 4 * (q - dq) + kg4 + 4;
                int xo = (b * 133 + j) * 8;
                bf16x8 ah = *(bf16x8*)&xh[xo];
                bf16x8 al = *(bf16x8*)&xl[xo];
#pragma unroll
                for (int nf = 0; nf < 2; ++nf) {
                    acc[ffi][nf] = __builtin_amdgcn_mfma_f32_16x16x32_bf16(ah, bh[nf], acc[ffi][nf], 0, 0, 0);
                    acc[ffi][nf] = __builtin_amdgcn_mfma_f32_16x16x32_bf16(al, bh[nf], acc[ffi][nf], 0, 0, 0);
                    acc[ffi][nf] = __builtin_amdgcn_mfma_f32_16x16x32_bf16(ah, bl[nf], acc[ffi][nf], 0, 0, 0);
                }
            }
        }
        __syncthreads();
    }

    float bsum[4] = {0, 0, 0, 0};
#pragma unroll
    for (int ffi = 0; ffi < 4; ++ffi) {
        int F = w + 4 * ffi;
#pragma unroll
        for (int nf = 0; nf < 2; ++nf) {
#pragma unroll
            for (int reg = 0; reg < 4; ++reg) {
                int mloc = 4 * kg4 + reg;
                int b = mloc & 7;
                int q = 2 * F + (mloc >> 3);
                int t = 32 * q + nf * 16 + lr;
                yT[((size_t)(b * 512 + c)) * 1024 + t] = acc[ffi][nf][reg];
                bsum[reg] += acc[ffi][nf][reg];
            }
        }
    }
#pragma unroll
    for (int off = 1; off < 16; off <<= 1) {
#pragma unroll
        for (int reg = 0; reg < 4; ++reg) bsum[reg] += __shfl_xor(bsum[reg], off, 64);
    }
    if (lr == 0) {
#pragma unroll
        for (int reg = 0; reg < 4; ++reg) ssh[w * 16 + kg4 * 4 + reg] = bsum[reg];
    }
    __syncthreads();
    if (tid < 8) {
        float tot = 0.0f;
        for (int w2 = 0; w2 < 4; ++w2) tot += ssh[w2 * 16 + tid] + ssh[w2 * 16 + 8 + tid];
        ssum[tid * 512 + c] = tot;
    }
}

__global__ __launch_bounds__(256) void se_kernel(const float* __restrict__ ssum,
                                                 const float* __restrict__ w1,
                                                 const float* __restrict__ b1,
                                                 const float* __restrict__ w2,
                                                 const float* __restrict__ b2,
                                                 float* __restrict__ g) {
    int b = blockIdx.x, tid = threadIdx.x;
    __shared__ float s_sh[512];
    __shared__ float part[256];
    __shared__ float h_sh[64];
    for (int c = tid; c < 512; c += 256) s_sh[c] = ssum[b * 512 + c] * (1.0f / 1024.0f);
    __syncthreads();
    int r = tid & 63, seg = tid >> 6;
    float p = 0.0f;
    for (int c = seg * 128; c < seg * 128 + 128; ++c) p += s_sh[c] * w1[r * 512 + c];
    part[tid] = p;
    __syncthreads();
    if (tid < 64) {
        float h = part[tid] + part[tid + 64] + part[tid + 128] + part[tid + 192] + b1[tid];
        h_sh[tid] = fmaxf(h, 0.0f);
    }
    __syncthreads();
    for (int c = tid; c < 512; c += 256) {
        float acc = b2[c];
#pragma unroll 8
        for (int rr = 0; rr < 64; ++rr) acc += h_sh[rr] * w2[c * 64 + rr];
        g[b * 512 + c] = 1.0f / (1.0f + expf(-acc));
    }
}

// ---------------------------------------------------------------------------
// fuse1t: merged transpose_y + fuse1 (unchanged).
// ---------------------------------------------------------------------------
__global__ __launch_bounds__(256) void fuse1t(const float* __restrict__ x,
                                              const float* __restrict__ yT,
                                              const float* __restrict__ g,
                                              const float* __restrict__ n1g,
                                              const float* __restrict__ n1b,
                                              unsigned short* __restrict__ y1b) {
    int ti = blockIdx.x, b = blockIdx.y, t0 = ti * 16, tid = threadIdx.x;
    __shared__ float tile[512 * 17];
    __shared__ float red1[256], red2[256];
    for (int i = tid; i < 2048; i += 256) {
        int c = i >> 2, tq = (i & 3) * 4;
        float4 v = *(const float4*)&yT[((size_t)(b * 512 + c)) * 1024 + t0 + tq];
        tile[c * 17 + tq + 0] = v.x;
        tile[c * 17 + tq + 1] = v.y;
        tile[c * 17 + tq + 2] = v.z;
        tile[c * 17 + tq + 3] = v.w;
    }
    __syncthreads();
    int tloc = tid >> 4, cg = tid & 15;
    int t = t0 + tloc;
    float vbuf[32];
    float s1 = 0.0f, s2 = 0.0f;
#pragma unroll
    for (int m = 0; m < 8; ++m) {
        int c = cg * 4 + 64 * m;
        float4 xv = *(const float4*)&x[((size_t)(b * 1024 + t)) * 512 + c];
        float4 gv = *(const float4*)&g[b * 512 + c];
        float v0 = xv.x + tile[(c + 0) * 17 + tloc] * gv.x;
        float v1 = xv.y + tile[(c + 1) * 17 + tloc] * gv.y;
        float v2 = xv.z + tile[(c + 2) * 17 + tloc] * gv.z;
        float v3 = xv.w + tile[(c + 3) * 17 + tloc] * gv.w;
        vbuf[m * 4 + 0] = v0; vbuf[m * 4 + 1] = v1;
        vbuf[m * 4 + 2] = v2; vbuf[m * 4 + 3] = v3;
        s1 += v0 + v1 + v2 + v3;
        s2 += v0 * v0 + v1 * v1 + v2 * v2 + v3 * v3;
    }
    red1[tid] = s1; red2[tid] = s2;
    __syncthreads();
    if (cg == 0) {
        float a1 = 0.0f, a2 = 0.0f;
#pragma unroll
        for (int k = 0; k < 16; ++k) { a1 += red1[tloc * 16 + k]; a2 += red2[tloc * 16 + k]; }
        red1[tloc * 16] = a1; red2[tloc * 16] = a2;
    }
    __syncthreads();
    float mean = red1[tloc * 16] * (1.0f / 512.0f);
    float var = red2[tloc * 16] * (1.0f / 512.0f) - mean * mean;
    float rstd = rsqrtf(var + 1e-5f);
#pragma unroll
    for (int m = 0; m < 8; ++m) {
        int c = cg * 4 + 64 * m;
        float4 g4 = *(const float4*)&n1g[c];
        float4 b4 = *(const float4*)&n1b[c];
        float o0 = (vbuf[m * 4 + 0] - mean) * rstd * g4.x + b4.x;
        float o1 = (vbuf[m * 4 + 1] - mean) * rstd * g4.y + b4.y;
        float o2 = (vbuf[m * 4 + 2] - mean) * rstd * g4.z + b4.z;
        float o3 = (vbuf[m * 4 + 3] - mean) * rstd * g4.w + b4.w;
        uint2 pk;
        pk.x = pk2(f2bf(o0), f2bf(o1));
        pk.y = pk2(f2bf(o2), f2bf(o3));
        *(uint2*)&y1b[((size_t)(b * 1024 + t)) * 512 + c] = pk;
    }
}

// ---------------------------------------------------------------------------
// GEMM1 + GLU — barrier-free register-direct: NO LDS, NO __syncthreads.
// Each wave owns a 32-row x (64a+64g)-col tile; A and B fragments are loaded
// straight global->VGPR (both contiguous 16B/lane in the native layouts).
// Waves pipeline independently; XCD swizzle keeps the working set (<=3MB)
// in the local XCD L2. Accumulation K-order identical to R12/R13.
// Grid 1024 blocks x 256 thr (4 independent waves/block).
// ---------------------------------------------------------------------------
__global__ __launch_bounds__(256) void gemm_glu(const unsigned short* __restrict__ A,
                                                const unsigned short* __restrict__ W,
                                                const float* __restrict__ bias,
                                                unsigned short* __restrict__ act) {
    const int K = 512;
    int id = blockIdx.x;                  // 0..1023
    int xcd = id & 7, local = id >> 3;    // local 0..127
    int mg = 8 * xcd + (local & 7);       // 0..63 (m-group of 128 rows)
    int nt = local >> 3;                  // 0..15
    int w = threadIdx.x >> 6, l = threadIdx.x & 63;
    int m0 = mg * 128 + w * 32;
    int n0 = nt * 64;
    int p = l >> 4, lr = l & 15;
    const unsigned short* pA[2];
#pragma unroll
    for (int rt = 0; rt < 2; ++rt)
        pA[rt] = A + (size_t)(m0 + rt * 16 + lr) * K + 8 * p;
    const unsigned short* pB[8];
#pragma unroll
    for (int ct = 0; ct < 4; ++ct) {
        pB[ct] = W + (size_t)(n0 + ct * 16 + lr) * K + 8 * p;
        pB[4 + ct] = W + (size_t)(1024 + n0 + ct * 16 + lr) * K + 8 * p;
    }
    f32x4 accA[2][4], accG[2][4];
#pragma unroll
    for (int rt = 0; rt < 2; ++rt)
#pragma unroll
        for (int ct = 0; ct < 4; ++ct) {
            accA[rt][ct] = (f32x4)0.0f;
            accG[rt][ct] = (f32x4)0.0f;
        }
#pragma unroll 4
    for (int kt = 0; kt < K; kt += 32) {
        bf16x8 af[2];
#pragma unroll
        for (int rt = 0; rt < 2; ++rt) af[rt] = *(const bf16x8*)(pA[rt] + kt);
        bf16x8 bA[4], bG[4];
#pragma unroll
        for (int ct = 0; ct < 4; ++ct) {
            bA[ct] = *(const bf16x8*)(pB[ct] + kt);
            bG[ct] = *(const bf16x8*)(pB[4 + ct] + kt);
        }
#pragma unroll
        for (int rt = 0; rt < 2; ++rt)
#pragma unroll
            for (int ct = 0; ct < 4; ++ct) {
                accA[rt][ct] = __builtin_amdgcn_mfma_f32_16x16x32_bf16(af[rt], bA[ct], accA[rt][ct], 0, 0, 0);
                accG[rt][ct] = __builtin_amdgcn_mfma_f32_16x16x32_bf16(af[rt], bG[ct], accG[rt][ct], 0, 0, 0);
            }
    }
#pragma unroll
    for (int rt = 0; rt < 2; ++rt)
#pragma unroll
        for (int ct = 0; ct < 4; ++ct) {
            int col = n0 + ct * 16 + lr;
            float ba = bias[col], bg = bias[1024 + col];
#pragma unroll
            for (int reg = 0; reg < 4; ++reg) {
                int row = m0 + rt * 16 + p * 4 + reg;
                float a = accA[rt][ct][reg] + ba;
                float gg = accG[rt][ct][reg] + bg;
                act[(size_t)row * 1024 + col] = f2bf(fast_gelu(a) * fast_sigmoid(gg));
            }
        }
}

// ---------------------------------------------------------------------------
// GEMM2 — same barrier-free register-direct structure. Wave tile 32x64.
// Grid 512 blocks x 256 thr.
// ---------------------------------------------------------------------------
__global__ __launch_bounds__(256) void gemm_plain(const unsigned short* __restrict__ A,
                                                  const unsigned short* __restrict__ W,
                                                  const float* __restrict__ bias,
                                                  float* __restrict__ Cout) {
    const int K = 1024, N = 512;
    int id = blockIdx.x;                  // 0..511
    int xcd = id & 7, local = id >> 3;    // local 0..63
    int mg = 8 * xcd + (local & 7);       // 0..63
    int nt = local >> 3;                  // 0..7
    int w = threadIdx.x >> 6, l = threadIdx.x & 63;
    int m0 = mg * 128 + w * 32;
    int n0 = nt * 64;
    int p = l >> 4, lr = l & 15;
    const unsigned short* pA[2];
#pragma unroll
    for (int rt = 0; rt < 2; ++rt)
        pA[rt] = A + (size_t)(m0 + rt * 16 + lr) * K + 8 * p;
    const unsigned short* pB[4];
#pragma unroll
    for (int ct = 0; ct < 4; ++ct)
        pB[ct] = W + (size_t)(n0 + ct * 16 + lr) * K + 8 * p;
    f32x4 acc[2][4];
#pragma unroll
    for (int rt = 0; rt < 2; ++rt)
#pragma unroll
        for (int ct = 0; ct < 4; ++ct) acc[rt][ct] = (f32x4)0.0f;
#pragma unroll 4
    for (int kt = 0; kt < K; kt += 32) {
        bf16x8 af[2];
#pragma unroll
        for (int rt = 0; rt < 2; ++rt) af[rt] = *(const bf16x8*)(pA[rt] + kt);
        bf16x8 bfr[4];
#pragma unroll
        for (int ct = 0; ct < 4; ++ct) bfr[ct] = *(const bf16x8*)(pB[ct] + kt);
#pragma unroll
        for (int rt = 0; rt < 2; ++rt)
#pragma unroll
            for (int ct = 0; ct < 4; ++ct)
                acc[rt][ct] = __builtin_amdgcn_mfma_f32_16x16x32_bf16(af[rt], bfr[ct], acc[rt][ct], 0, 0, 0);
    }
#pragma unroll
    for (int rt = 0; rt < 2; ++rt)
#pragma unroll
        for (int ct = 0; ct < 4; ++ct) {
            int col = n0 + ct * 16 + lr;
            float bb = bias[col];
#pragma unroll
            for (int reg = 0; reg < 4; ++reg) {
                int row = m0 + rt * 16 + p * 4 + reg;
                Cout[(size_t)row * N + col] = acc[rt][ct][reg] + bb;
            }
        }
}

// fuse2: z2 = LN(y1+z, mixn); out = LN(y1+z2, n2). y1 read as bf16.
__global__ __launch_bounds__(128) void fuse2_kernel(const unsigned short* __restrict__ y1b,
                                                    const float* __restrict__ z,
                                                    const float* __restrict__ mg,
                                                    const float* __restrict__ mb,
                                                    const float* __restrict__ g2,
                                                    const float* __restrict__ b2v,
                                                    float* __restrict__ out) {
    int row = blockIdx.x, tid = threadIdx.x, c = tid * 4;
    __shared__ float r1[2], r2[2];
    uint2 yu = *(const uint2*)&y1b[(size_t)row * 512 + c];
    float4 a;
    a.x = __uint_as_float(yu.x << 16);
    a.y = __uint_as_float(yu.x & 0xffff0000u);
    a.z = __uint_as_float(yu.y << 16);
    a.w = __uint_as_float(yu.y & 0xffff0000u);
    float4 zv = *(const float4*)&z[(size_t)row * 512 + c];
    float4 t1;
    t1.x = a.x + zv.x; t1.y = a.y + zv.y; t1.z = a.z + zv.z; t1.w = a.w + zv.w;
    float s1 = t1.x + t1.y + t1.z + t1.w;
    float s2 = t1.x * t1.x + t1.y * t1.y + t1.z * t1.z + t1.w * t1.w;
#pragma unroll
    for (int off = 32; off > 0; off >>= 1) {
        s1 += __shfl_down(s1, off, 64);
        s2 += __shfl_down(s2, off, 64);
    }
    if ((tid & 63) == 0) { r1[tid >> 6] = s1; r2[tid >> 6] = s2; }
    __syncthreads();
    float mean = (r1[0] + r1[1]) * (1.0f / 512.0f);
    float var = (r2[0] + r2[1]) * (1.0f / 512.0f) - mean * mean;
    float rstd = rsqrtf(var + 1e-5f);
    float4 mg4 = *(const float4*)&mg[c];
    float4 mb4 = *(const float4*)&mb[c];
    float4 t2;
    t2.x = a.x + ((t1.x - mean) * rstd * mg4.x + mb4.x);
    t2.y = a.y + ((t1.y - mean) * rstd * mg4.y + mb4.y);
    t2.z = a.z + ((t1.z - mean) * rstd * mg4.z + mb4.z);
    t2.w = a.w + ((t1.w - mean) * rstd * mg4.w + mb4.w);
    __syncthreads();
    s1 = t2.x + t2.y + t2.z + t2.w;
    s2 = t2.x * t2.x + t2.y * t2.y + t2.z * t2.z + t2.w * t2.w;
#pragma unroll
    for (int off = 32; off > 0; off >>= 1) {
        s1 += __shfl_down(s1, off, 64);
        s2 += __shfl_down(s2, off, 64);
    }
    if ((tid & 63) == 0) { r1[tid >> 6] = s1; r2[tid >> 6] = s2; }
    __syncthreads();
    float mean2 = (r1[0] + r1[1]) * (1.0f / 512.0f);
    float var2 = (r2[0] + r2[1]) * (1.0f / 512.0f) - mean2 * mean2;
    float rstd2 = rsqrtf(var2 + 1e-5f);
    float4 gg = *(const float4*)&g2[c];
    float4 bb = *(const float4*)&b2v[c];
    float4 o;
    o.x = (t2.x - mean2) * rstd2 * gg.x + bb.x;
    o.y = (t2.y - mean2) * rstd2 * gg.y + bb.y;
    o.z = (t2.z - mean2) * rstd2 * gg.z + bb.z;
    o.w = (t2.w - mean2) * rstd2 * gg.w + bb.w;
    *(float4*)&out[(size_t)row * 512 + c] = o;
}

// ---------------------------------------------------------------------------
// Workspace layout (float offsets), same map as R13.
// ---------------------------------------------------------------------------
extern "C" void kernel_launch(void* const* d_in, const int* in_sizes, int n_in,
                              void* d_out, int out_size, void* d_ws, size_t ws_size,
                              hipStream_t stream) {
    (void)in_sizes; (void)n_in; (void)out_size; (void)ws_size;
    const float* x      = (const float*)d_in[0];
    const float* Bp     = (const float*)d_in[1];
    const float* Cp     = (const float*)d_in[2];
    const float* Dp     = (const float*)d_in[3];
    const float* log_dt = (const float*)d_in[4];
    const float* se_w1  = (const float*)d_in[5];
    const float* se_b1  = (const float*)d_in[6];
    const float* se_w2  = (const float*)d_in[7];
    const float* se_b2  = (const float*)d_in[8];
    const float* n1g    = (const float*)d_in[9];
    const float* n1b    = (const float*)d_in[10];
    const float* up_w   = (const float*)d_in[11];
    const float* up_b   = (const float*)d_in[12];
    const float* dn_w   = (const float*)d_in[13];
    const float* dn_b   = (const float*)d_in[14];
    const float* mxg    = (const float*)d_in[15];
    const float* mxb    = (const float*)d_in[16];
    const float* n2g    = (const float*)d_in[17];
    const float* n2b    = (const float*)d_in[18];

    float* ws = (float*)d_ws;
    float* Kr   = ws + 0;          //   524,288
    float* ssum = ws + 524352;     //     4,096
    float* gbuf = ws + 528448;     //     4,096
    unsigned short* up_wb = (unsigned short*)(ws + 532544);   // 524,288 fl
    unsigned short* dn_wb = (unsigned short*)(ws + 1056832);  // 262,144 fl
    float* Pow  = ws + 1450048;    //   163,840
    unsigned short* Bb_h = (unsigned short*)(ws + 1613888);   // 65,536 fl each
    unsigned short* Bb_l = (unsigned short*)(ws + 1679424);
    unsigned short* Cp_h = (unsigned short*)(ws + 1744960);
    unsigned short* Cp_l = (unsigned short*)(ws + 1810496);
    unsigned short* Pst_h = (unsigned short*)(ws + 1876032);  // 262,144 fl each
    unsigned short* Pst_l = (unsigned short*)(ws + 2138176);
    unsigned short* Qst_h = (unsigned short*)(ws + 2400320);
    unsigned short* Qst_l = (unsigned short*)(ws + 2662464);
    float* xT   = ws + 5021760;    //  4,194,304
    float* yT2  = ws + 9216064;    //  4,194,304
    float* zb   = ws + 13410368;   //  4,194,304
    unsigned short* act = (unsigned short*)(ws + 5021760);    // alias xT after conv
    unsigned short* y1b = (unsigned short*)(ws + 20971520);   // fresh region
    unsigned short* U_h2 = (unsigned short*)(ws + 25165824);
    unsigned short* U_l2 = (unsigned short*)(ws + 27262976);
    unsigned short* V_h2 = (unsigned short*)(ws + 29360128);
    unsigned short* V_l2 = (unsigned short*)(ws + 31457280);
    float* outp = (float*)d_out;

    hipLaunchKernelGGL(front_kernel, dim3(4940), dim3(256), 0, stream,
                       log_dt, Bp, up_w, dn_w, Cp, x,
                       Pow, Bb_h, Bb_l, up_wb, dn_wb, Cp_h, Cp_l, xT);
    hipLaunchKernelGGL(power_mats, dim3(64, 4), dim3(256), 0, stream, Pow, Pst_h, Pst_l, Qst_h, Qst_l);
    hipLaunchKernelGGL(kgemm_uv2, dim3(4, 32, 8), dim3(256), 0, stream,
                       Bb_h, Bb_l, Pst_h, Pst_l, Cp_h, Cp_l, Qst_h, Qst_l, V_h2, V_l2, U_h2, U_l2);
    hipLaunchKernelGGL(kgemm_kr, dim3(512), dim3(256), 0, stream, U_h2, U_l2, V_h2, V_l2, Dp, Kr);
    hipLaunchKernelGGL(conv_mfma, dim3(512), dim3(256), 0, stream, xT, Kr, yT2, ssum);
    hipLaunchKernelGGL(se_kernel, dim3(8), dim3(256), 0, stream, ssum, se_w1, se_b1, se_w2, se_b2, gbuf);
    hipLaunchKernelGGL(fuse1t, dim3(64, 8), dim3(256), 0, stream, x, yT2, gbuf, n1g, n1b, y1b);
    hipLaunchKernelGGL(gemm_glu, dim3(1024), dim3(256), 0, stream, y1b, up_wb, up_b, act);
    hipLaunchKernelGGL(gemm_plain, dim3(512), dim3(256), 0, stream, act, dn_wb, dn_b, zb);
    hipLaunchKernelGGL(fuse2_kernel, dim3(8192), dim3(128), 0, stream, y1b, zb, mxg, mxb, n2g, n2b, outp);
}

// Round 15
// 203.541 us; speedup vs baseline: 1.3346x; 1.3346x over previous
//
#include <hip/hip_runtime.h>
#include <math.h>

// Sizes: B=8, L=1024, D=512, N=64, NC=4, HIDDEN=1024, up rows=2048, R=64

typedef short bf16x8 __attribute__((ext_vector_type(8)));
typedef float f32x4 __attribute__((ext_vector_type(4)));

__device__ __forceinline__ float fast_sigmoid(float x) { return 1.0f / (1.0f + __expf(-x)); }
__device__ __forceinline__ float fast_gelu(float x) {
    float u = 0.7978845608f * (x + 0.044715f * x * x * x);
    float t = 1.0f - 2.0f / (1.0f + __expf(2.0f * u));
    return 0.5f * x * (1.0f + t);
}
__device__ __forceinline__ unsigned short f2bf(float f) {
    unsigned u = __float_as_uint(f);
    unsigned r = (u + 0x7FFFu + ((u >> 16) & 1u)) >> 16;
    return (unsigned short)r;
}
__device__ __forceinline__ unsigned pk2(unsigned short a, unsigned short b) {
    return (unsigned)a | ((unsigned)b << 16);
}
__device__ __forceinline__ void gload16(const void* g, void* l) {
    __builtin_amdgcn_global_load_lds((const __attribute__((address_space(1))) unsigned int*)g,
                                     (__attribute__((address_space(3))) unsigned int*)l, 16, 0, 0);
}

// ---------------------------------------------------------------------------
// front_kernel: prep_comp + compute_bbar + convert_all + transpose_x fused
// by block range (R13).
// ---------------------------------------------------------------------------
__global__ __launch_bounds__(256) void front_kernel(const float* __restrict__ log_dt,
                                                    const float* __restrict__ Bp,
                                                    const float* __restrict__ up_w,
                                                    const float* __restrict__ dn_w,
                                                    const float* __restrict__ Cp,
                                                    const float* __restrict__ x,
                                                    float* __restrict__ Pow,
                                                    unsigned short* __restrict__ Bb_h,
                                                    unsigned short* __restrict__ Bb_l,
                                                    unsigned short* __restrict__ up_wb,
                                                    unsigned short* __restrict__ dn_wb,
                                                    unsigned short* __restrict__ Cp_h,
                                                    unsigned short* __restrict__ Cp_l,
                                                    float* __restrict__ xT) {
    __shared__ __align__(16) float smem[16640];
    int bid = blockIdx.x, tid = threadIdx.x;
    if (bid < 4) {
        float* M1 = smem;
        float* M1T = smem + 4096;
        float* M2 = smem + 8192;
        float* M2T = smem + 12288;
        int comp = bid;
        float ldt = log_dt[comp];
        float dt = log1pf(expf(ldt)) + 1e-6f;
        float hdt = 0.5f * dt;
        if (tid < 64) {
            int j = tid;
            float sqj = sqrtf(2.0f * (float)j + 1.0f);
            float S = 0.0f;
            for (int i = 0; i < 64; ++i) {
                float sqi = sqrtf(2.0f * (float)i + 1.0f);
                float r = (i == j) ? (1.0f - hdt * (float)(i + 1))
                                   : ((i > j) ? (-hdt * sqi * sqj) : 0.0f);
                float X = (r - hdt * sqi * S) / (1.0f + hdt * (float)(i + 1));
                M1[i * 64 + j] = X;
                M1T[j * 64 + i] = X;
                S += sqi * X;
            }
        }
        __syncthreads();
        for (int ii = tid; ii < 4096; ii += 256) Pow[(size_t)comp * 40960 + ii] = M1[ii];
        float* cur = M1; float* curT = M1T; float* nxt = M2; float* nxtT = M2T;
        int ti = tid >> 4, tj = tid & 15;
        for (int s = 1; s <= 9; ++s) {
            float c[4][4] = {{0}};
#pragma unroll 8
            for (int k = 0; k < 64; ++k) {
                float4 a = *(const float4*)&curT[k * 64 + ti * 4];
                float4 b = *(const float4*)&cur[k * 64 + tj * 4];
                c[0][0] += a.x * b.x; c[0][1] += a.x * b.y; c[0][2] += a.x * b.z; c[0][3] += a.x * b.w;
                c[1][0] += a.y * b.x; c[1][1] += a.y * b.y; c[1][2] += a.y * b.z; c[1][3] += a.y * b.w;
                c[2][0] += a.z * b.x; c[2][1] += a.z * b.y; c[2][2] += a.z * b.z; c[2][3] += a.z * b.w;
                c[3][0] += a.w * b.x; c[3][1] += a.w * b.y; c[3][2] += a.w * b.z; c[3][3] += a.w * b.w;
            }
#pragma unroll
            for (int r = 0; r < 4; ++r) {
                float4 row; row.x = c[r][0]; row.y = c[r][1]; row.z = c[r][2]; row.w = c[r][3];
                *(float4*)&nxt[(ti * 4 + r) * 64 + tj * 4] = row;
                float4 colv; colv.x = c[0][r]; colv.y = c[1][r]; colv.z = c[2][r]; colv.w = c[3][r];
                *(float4*)&nxtT[(tj * 4 + r) * 64 + ti * 4] = colv;
            }
            __syncthreads();
            for (int ii = tid; ii < 4096; ii += 256) Pow[(size_t)comp * 40960 + s * 4096 + ii] = nxt[ii];
            float* t0 = cur; cur = nxt; nxt = t0;
            float* t1 = curT; curT = nxtT; nxtT = t1;
            __syncthreads();
        }
    } else if (bid < 12) {
        int gid = (bid - 4) * 256 + tid;
        int comp = gid >> 9;
        float ldt = log_dt[comp];
        float dt = log1pf(expf(ldt)) + 1e-6f;
        float hdt = 0.5f * dt;
        const float* bp = Bp + (size_t)gid * 64;
        unsigned short* oh = Bb_h + (size_t)gid * 64;
        unsigned short* ol = Bb_l + (size_t)gid * 64;
        float S = 0.0f;
        for (int i = 0; i < 64; ++i) {
            float sqi = sqrtf(2.0f * (float)i + 1.0f);
            float y = (dt * bp[i] - hdt * sqi * S) / (1.0f + hdt * (float)(i + 1));
            unsigned short h = f2bf(y);
            oh[i] = h;
            ol[i] = f2bf(y - __uint_as_float((unsigned)h << 16));
            S += sqi * y;
        }
    } else if (bid < 844) {
        int i = (bid - 12) * 256 + tid;
        if (i < 196608) {
            const float* src = (i < 131072) ? up_w : dn_w;
            unsigned short* dst = (i < 131072) ? up_wb : dn_wb;
            int j = (i < 131072) ? i : (i - 131072);
            float4 a = ((const float4*)src)[2 * j];
            float4 b = ((const float4*)src)[2 * j + 1];
            uint4 o;
            o.x = pk2(f2bf(a.x), f2bf(a.y));
            o.y = pk2(f2bf(a.z), f2bf(a.w));
            o.z = pk2(f2bf(b.x), f2bf(b.y));
            o.w = pk2(f2bf(b.z), f2bf(b.w));
            *(uint4*)&dst[(size_t)j * 8] = o;
        } else if (i < 212992) {
            int j = i - 196608;
            float4 a = ((const float4*)Cp)[2 * j];
            float4 b = ((const float4*)Cp)[2 * j + 1];
            float vv[8] = {a.x, a.y, a.z, a.w, b.x, b.y, b.z, b.w};
            unsigned short hs[8], ls[8];
#pragma unroll
            for (int k = 0; k < 8; ++k) {
                unsigned short h = f2bf(vv[k]);
                hs[k] = h;
                ls[k] = f2bf(vv[k] - __uint_as_float((unsigned)h << 16));
            }
            uint4 ho, lo;
            ho.x = pk2(hs[0], hs[1]); ho.y = pk2(hs[2], hs[3]); ho.z = pk2(hs[4], hs[5]); ho.w = pk2(hs[6], hs[7]);
            lo.x = pk2(ls[0], ls[1]); lo.y = pk2(ls[2], ls[3]); lo.z = pk2(ls[4], ls[5]); lo.w = pk2(ls[6], ls[7]);
            *(uint4*)&Cp_h[(size_t)j * 8] = ho;
            *(uint4*)&Cp_l[(size_t)j * 8] = lo;
        }
    } else {
        int li = bid - 844;
        int bx = li & 31, by = (li >> 5) & 15, bz = li >> 9;
        float* tile = smem;
        int r0 = bx * 32, c0 = by * 32, b = bz;
        int tx = tid & 31, ty = tid >> 5;
#pragma unroll
        for (int m = 0; m < 4; ++m)
            tile[(ty + 8 * m) * 33 + tx] = x[((size_t)b * 1024 + r0 + ty + 8 * m) * 512 + c0 + tx];
        __syncthreads();
#pragma unroll
        for (int m = 0; m < 4; ++m)
            xT[((size_t)b * 512 + c0 + ty + 8 * m) * 1024 + r0 + tx] = tile[tx * 33 + ty + 8 * m];
    }
}

// ---------------------------------------------------------------------------
// power_mats: unchanged.
// ---------------------------------------------------------------------------
__global__ __launch_bounds__(256) void power_mats(const float* __restrict__ Pow,
                                                  unsigned short* __restrict__ Pst_h,
                                                  unsigned short* __restrict__ Pst_l,
                                                  unsigned short* __restrict__ Qst_h,
                                                  unsigned short* __restrict__ Qst_l) {
    int idx = blockIdx.x, comp = blockIdx.y, tid = threadIdx.x;
    __shared__ __align__(16) float R[4096], RT[4096], R2[4096], R2T[4096], SbT[4096];
    int isP = (idx < 32) ? 1 : 0;
    int f = isP ? idx : (idx - 32);
    int base_s = isP ? 0 : 5;
    const float* PowC = Pow + (size_t)comp * 40960;
    int i_ = tid & 63, kc = (tid >> 6) * 16;
    float* cur = R; float* curT = RT; float* nx = R2; float* nxT = R2T;
    if (f == 0) {
        for (int ii = tid; ii < 4096; ii += 256) {
            float v = ((ii >> 6) == (ii & 63)) ? 1.0f : 0.0f;
            R[ii] = v; RT[ii] = v;
        }
        __syncthreads();
    } else {
        int b0 = __ffs(f) - 1;
        const float* S0 = PowC + (size_t)(base_s + b0) * 4096;
#pragma unroll
        for (int j = 0; j < 16; j += 4) {
            float4 v = *(const float4*)&S0[i_ * 64 + kc + j];
            *(float4*)&R[i_ * 64 + kc + j] = v;
            RT[(kc + j + 0) * 64 + i_] = v.x;
            RT[(kc + j + 1) * 64 + i_] = v.y;
            RT[(kc + j + 2) * 64 + i_] = v.z;
            RT[(kc + j + 3) * 64 + i_] = v.w;
        }
        int rem = f & ~(1 << b0);
        int ti = tid >> 4, tj = tid & 15;
        __syncthreads();
        while (rem) {
            int b = __ffs(rem) - 1; rem &= rem - 1;
            const float* Sb = PowC + (size_t)(base_s + b) * 4096;
#pragma unroll
            for (int j = 0; j < 16; j += 4) {
                float4 v = *(const float4*)&Sb[i_ * 64 + kc + j];
                SbT[(kc + j + 0) * 64 + i_] = v.x;
                SbT[(kc + j + 1) * 64 + i_] = v.y;
                SbT[(kc + j + 2) * 64 + i_] = v.z;
                SbT[(kc + j + 3) * 64 + i_] = v.w;
            }
            __syncthreads();
            float c[4][4] = {{0}};
#pragma unroll 8
            for (int k = 0; k < 64; ++k) {
                float4 a = *(const float4*)&SbT[k * 64 + ti * 4];
                float4 b4 = *(const float4*)&cur[k * 64 + tj * 4];
                c[0][0] += a.x * b4.x; c[0][1] += a.x * b4.y; c[0][2] += a.x * b4.z; c[0][3] += a.x * b4.w;
                c[1][0] += a.y * b4.x; c[1][1] += a.y * b4.y; c[1][2] += a.y * b4.z; c[1][3] += a.y * b4.w;
                c[2][0] += a.z * b4.x; c[2][1] += a.z * b4.y; c[2][2] += a.z * b4.z; c[2][3] += a.z * b4.w;
                c[3][0] += a.w * b4.x; c[3][1] += a.w * b4.y; c[3][2] += a.w * b4.z; c[3][3] += a.w * b4.w;
            }
#pragma unroll
            for (int r = 0; r < 4; ++r) {
                float4 row; row.x = c[r][0]; row.y = c[r][1]; row.z = c[r][2]; row.w = c[r][3];
                *(float4*)&nx[(ti * 4 + r) * 64 + tj * 4] = row;
                float4 colv; colv.x = c[0][r]; colv.y = c[1][r]; colv.z = c[2][r]; colv.w = c[3][r];
                *(float4*)&nxT[(tj * 4 + r) * 64 + ti * 4] = colv;
            }
            __syncthreads();
            float* t0 = cur; cur = nx; nx = t0;
            float* t1 = curT; curT = nxT; nxT = t1;
        }
    }
    const float* src = isP ? cur : curT;
    int outrow = isP ? idx : (idx - 32);
    unsigned short* dh = (isP ? Pst_h : Qst_h) + (size_t)comp * 131072 + (size_t)outrow * 4096;
    unsigned short* dl = (isP ? Pst_l : Qst_l) + (size_t)comp * 131072 + (size_t)outrow * 4096;
    for (int ii = tid * 8; ii < 4096; ii += 2048) {
        float4 v0 = *(const float4*)&src[ii];
        float4 v1 = *(const float4*)&src[ii + 4];
        float vv[8] = {v0.x, v0.y, v0.z, v0.w, v1.x, v1.y, v1.z, v1.w};
        unsigned short hs[8], ls[8];
#pragma unroll
        for (int j = 0; j < 8; ++j) {
            unsigned short h = f2bf(vv[j]);
            hs[j] = h;
            ls[j] = f2bf(vv[j] - __uint_as_float((unsigned)h << 16));
        }
        uint4 ho, lo;
        ho.x = pk2(hs[0], hs[1]); ho.y = pk2(hs[2], hs[3]); ho.z = pk2(hs[4], hs[5]); ho.w = pk2(hs[6], hs[7]);
        lo.x = pk2(ls[0], ls[1]); lo.y = pk2(ls[2], ls[3]); lo.z = pk2(ls[4], ls[5]); lo.w = pk2(ls[6], ls[7]);
        *(uint4*)&dh[ii] = ho;
        *(uint4*)&dl[ii] = lo;
    }
}

// ---------------------------------------------------------------------------
// kgemm_uv2: merged U and V (unchanged).
// ---------------------------------------------------------------------------
__global__ __launch_bounds__(256) void kgemm_uv2(const unsigned short* __restrict__ Bb_h,
                                                 const unsigned short* __restrict__ Bb_l,
                                                 const unsigned short* __restrict__ Pst_h,
                                                 const unsigned short* __restrict__ Pst_l,
                                                 const unsigned short* __restrict__ Cp_h,
                                                 const unsigned short* __restrict__ Cp_l,
                                                 const unsigned short* __restrict__ Qst_h,
                                                 const unsigned short* __restrict__ Qst_l,
                                                 unsigned short* __restrict__ V_h,
                                                 unsigned short* __restrict__ V_l,
                                                 unsigned short* __restrict__ U_h,
                                                 unsigned short* __restrict__ U_l) {
    int zz = blockIdx.z;
    int isV = (zz < 4) ? 1 : 0;
    int comp = isV ? zz : (zz - 4);
    const unsigned short* Ah = isV ? Bb_h : Cp_h;
    const unsigned short* Al = isV ? Bb_l : Cp_l;
    const unsigned short* Bh = isV ? Pst_h : Qst_h;
    const unsigned short* Bl = isV ? Pst_l : Qst_l;
    unsigned short* Ch = isV ? V_h : U_h;
    unsigned short* Cl = isV ? V_l : U_l;
    int m0 = blockIdx.x * 128, n0 = blockIdx.y * 64;
    int tid = threadIdx.x, w = tid >> 6, l = tid & 63;
    __shared__ __align__(16) short Ash[8192], Asl[8192], Bsh[4096], Bsl[4096];
    const unsigned short* Abh = Ah + (size_t)comp * 32768;
    const unsigned short* Abl = Al + (size_t)comp * 32768;
    const unsigned short* Bbh = Bh + (size_t)comp * 131072;
    const unsigned short* Bbl = Bl + (size_t)comp * 131072;
#pragma unroll
    for (int i = 0; i < 4; ++i) {
        int cid = tid + 256 * i;
        int row = cid >> 3, slot = cid & 7;
        int goff = (m0 + row) * 64 + slot * 8;
        int loff = row * 64 + (slot ^ (row & 7)) * 8;
        *(uint4*)&Ash[loff] = *(const uint4*)(Abh + goff);
        *(uint4*)&Asl[loff] = *(const uint4*)(Abl + goff);
    }
#pragma unroll
    for (int i = 0; i < 2; ++i) {
        int cid = tid + 256 * i;
        int row = cid >> 3, slot = cid & 7;
        int goff = (n0 + row) * 64 + slot * 8;
        int loff = row * 64 + (slot ^ (row & 7)) * 8;
        *(uint4*)&Bsh[loff] = *(const uint4*)(Bbh + goff);
        *(uint4*)&Bsl[loff] = *(const uint4*)(Bbl + goff);
    }
    __syncthreads();
    int p = l >> 4, lr = l & 15;
    f32x4 acc[2][4];
#pragma unroll
    for (int rt = 0; rt < 2; ++rt)
#pragma unroll
        for (int ct = 0; ct < 4; ++ct) acc[rt][ct] = (f32x4)0.0f;
#pragma unroll
    for (int ks = 0; ks < 2; ++ks) {
        bf16x8 ah2[2], al2[2], bh2[4], bl2[4];
#pragma unroll
        for (int rt = 0; rt < 2; ++rt) {
            int row = w * 32 + rt * 16 + lr;
            int off = row * 64 + ((ks * 4 + p) ^ (row & 7)) * 8;
            ah2[rt] = *(bf16x8*)&Ash[off];
            al2[rt] = *(bf16x8*)&Asl[off];
        }
#pragma unroll
        for (int ct = 0; ct < 4; ++ct) {
            int cr = ct * 16 + lr;
            int off = cr * 64 + ((ks * 4 + p) ^ (cr & 7)) * 8;
            bh2[ct] = *(bf16x8*)&Bsh[off];
            bl2[ct] = *(bf16x8*)&Bsl[off];
        }
#pragma unroll
        for (int rt = 0; rt < 2; ++rt)
#pragma unroll
            for (int ct = 0; ct < 4; ++ct) {
                acc[rt][ct] = __builtin_amdgcn_mfma_f32_16x16x32_bf16(ah2[rt], bh2[ct], acc[rt][ct], 0, 0, 0);
                acc[rt][ct] = __builtin_amdgcn_mfma_f32_16x16x32_bf16(ah2[rt], bl2[ct], acc[rt][ct], 0, 0, 0);
                acc[rt][ct] = __builtin_amdgcn_mfma_f32_16x16x32_bf16(al2[rt], bh2[ct], acc[rt][ct], 0, 0, 0);
            }
    }
#pragma unroll
    for (int rt = 0; rt < 2; ++rt)
#pragma unroll
        for (int ct = 0; ct < 4; ++ct) {
#pragma unroll
            for (int reg = 0; reg < 4; ++reg) {
                int row = m0 + w * 32 + rt * 16 + p * 4 + reg;
                int col = n0 + ct * 16 + lr;
                float v = acc[rt][ct][reg];
                unsigned short h = f2bf(v);
                unsigned short lo2 = f2bf(v - __uint_as_float((unsigned)h << 16));
                size_t o = (size_t)comp * 1048576 + (size_t)row * 2048 + col;
                Ch[o] = h;
                Cl[o] = lo2;
            }
        }
}

// ---------------------------------------------------------------------------
// kgemm_kr: fused kgemm_k + reduce_K (unchanged).
// ---------------------------------------------------------------------------
__global__ __launch_bounds__(256) void kgemm_kr(const unsigned short* __restrict__ Uh,
                                                const unsigned short* __restrict__ Ul,
                                                const unsigned short* __restrict__ Vh,
                                                const unsigned short* __restrict__ Vl,
                                                const float* __restrict__ Dp,
                                                float* __restrict__ Kr) {
    int tid = threadIdx.x, w = tid >> 6, l = tid & 63;
    int d = blockIdx.x;
    int g = w * 512 + d;
    int p = l >> 4, lr = l & 15;
    __shared__ float ksh[4096];
    const unsigned short* ubh = Uh + (size_t)g * 2048;
    const unsigned short* ubl = Ul + (size_t)g * 2048;
    const unsigned short* vbh = Vh + (size_t)g * 2048;
    const unsigned short* vbl = Vl + (size_t)g * 2048;
    f32x4 acc[2][2];
    acc[0][0] = (f32x4)0.0f; acc[0][1] = (f32x4)0.0f;
    acc[1][0] = (f32x4)0.0f; acc[1][1] = (f32x4)0.0f;
#pragma unroll
    for (int ks = 0; ks < 2; ++ks) {
        bf16x8 uh2[2], ul2[2], vh2[2], vl2[2];
#pragma unroll
        for (int mt = 0; mt < 2; ++mt) {
            int off = (mt * 16 + lr) * 64 + ks * 32 + p * 8;
            uh2[mt] = *(const bf16x8*)(ubh + off);
            ul2[mt] = *(const bf16x8*)(ubl + off);
            vh2[mt] = *(const bf16x8*)(vbh + off);
            vl2[mt] = *(const bf16x8*)(vbl + off);
        }
#pragma unroll
        for (int mt = 0; mt < 2; ++mt)
#pragma unroll
            for (int nt = 0; nt < 2; ++nt) {
                acc[mt][nt] = __builtin_amdgcn_mfma_f32_16x16x32_bf16(uh2[mt], vh2[nt], acc[mt][nt], 0, 0, 0);
                acc[mt][nt] = __builtin_amdgcn_mfma_f32_16x16x32_bf16(uh2[mt], vl2[nt], acc[mt][nt], 0, 0, 0);
                acc[mt][nt] = __builtin_amdgcn_mfma_f32_16x16x32_bf16(ul2[mt], vh2[nt], acc[mt][nt], 0, 0, 0);
            }
    }
#pragma unroll
    for (int mt = 0; mt < 2; ++mt)
#pragma unroll
        for (int nt = 0; nt < 2; ++nt)
#pragma unroll
            for (int reg = 0; reg < 4; ++reg) {
                int q = mt * 16 + p * 4 + reg;
                int r = nt * 16 + lr;
                ksh[w * 1024 + q * 32 + r] = acc[mt][nt][reg];
            }
    __syncthreads();
#pragma unroll
    for (int j = 0; j < 4; ++j) {
        int ll = tid * 4 + j;
        float s = ksh[ll] + ksh[1024 + ll] + ksh[2048 + ll] + ksh[3072 + ll];
        if (ll == 0) s += Dp[d] + Dp[512 + d] + Dp[1024 + d] + Dp[1536 + d];
        Kr[(size_t)d * 1024 + (1023 - ll)] = s;
    }
}

// ---------------------------------------------------------------------------
// MFMA depthwise conv (unchanged).
// ---------------------------------------------------------------------------
__global__ __launch_bounds__(256) void conv_mfma(const float* __restrict__ xT,
                                                 const float* __restrict__ Kr,
                                                 float* __restrict__ yT,
                                                 float* __restrict__ ssum) {
    int c = blockIdx.x, tid = threadIdx.x;
    int w = tid >> 6, l = tid & 63;
    __shared__ __align__(16) float krp[1088];
    __shared__ __align__(16) short xh[8512], xl[8512];
    __shared__ __align__(16) short gh[10240], gl[10240];
    __shared__ float ssh[64];

    {
        float4 kv = *(const float4*)&Kr[(size_t)c * 1024 + tid * 4];
        *(float4*)&krp[32 + tid * 4] = kv;
        if (tid < 8) *(float4*)&krp[tid * 4] = make_float4(0, 0, 0, 0);
        else if (tid < 16) *(float4*)&krp[1056 + (tid - 8) * 4] = make_float4(0, 0, 0, 0);
    }
    if (tid < 32) {
        int b = tid >> 2, g = tid & 3;
        uint4 z = {0, 0, 0, 0};
        *(uint4*)&xh[(b * 133 + g) * 8] = z;
    } else if (tid < 64) {
        int t2 = tid - 32; int b = t2 >> 2, g = t2 & 3;
        uint4 z = {0, 0, 0, 0};
        *(uint4*)&xl[(b * 133 + g) * 8] = z;
    }
#pragma unroll
    for (int i = 0; i < 4; ++i) {
        int gid = tid + 256 * i;
        int b = gid >> 7, gt = gid & 127;
        const float* src = &xT[((size_t)(b * 512 + c)) * 1024 + gt * 8];
        float4 v0 = *(const float4*)src;
        float4 v1 = *(const float4*)(src + 4);
        float vv[8] = {v0.x, v0.y, v0.z, v0.w, v1.x, v1.y, v1.z, v1.w};
        unsigned short hsv[8], lsv[8];
#pragma unroll
        for (int j2 = 0; j2 < 8; ++j2) {
            unsigned short h = f2bf(vv[j2]);
            hsv[j2] = h;
            lsv[j2] = f2bf(vv[j2] - __uint_as_float((unsigned)h << 16));
        }
        uint4 hh, ll;
        hh.x = pk2(hsv[0], hsv[1]); hh.y = pk2(hsv[2], hsv[3]);
        hh.z = pk2(hsv[4], hsv[5]); hh.w = pk2(hsv[6], hsv[7]);
        ll.x = pk2(lsv[0], lsv[1]); ll.y = pk2(lsv[2], lsv[3]);
        ll.z = pk2(lsv[4], lsv[5]); ll.w = pk2(lsv[6], lsv[7]);
        int off = (b * 133 + 4 + gt) * 8;
        *(uint4*)&xh[off] = hh;
        *(uint4*)&xl[off] = ll;
    }
    __syncthreads();

    f32x4 acc[4][2];
#pragma unroll
    for (int i = 0; i < 4; ++i) { acc[i][0] = (f32x4)0.0f; acc[i][1] = (f32x4)0.0f; }

    int lr = l & 15, kg4 = l >> 4;
    for (int ch = 0; ch < 4; ++ch) {
        int dq0 = ch * 8;
        {
            int dqloc = tid >> 5, n = tid & 31, dq = dq0 + dqloc;
            int s0 = 32 * dq + n + 1;
            int a0 = s0 & ~3, sh = s0 & 3;
            float ff[36];
#pragma unroll
            for (int i = 0; i < 9; ++i) *(float4*)&ff[i * 4] = *(const float4*)&krp[a0 + i * 4];
            unsigned short hsv[32], lsv[32];
#pragma unroll
            for (int k = 0; k < 32; ++k) {
                int j2 = 31 - k;
                float v = (sh == 0) ? ff[j2] : (sh == 1) ? ff[j2 + 1] : (sh == 2) ? ff[j2 + 2] : ff[j2 + 3];
                unsigned short h = f2bf(v);
                hsv[k] = h;
                lsv[k] = f2bf(v - __uint_as_float((unsigned)h << 16));
            }
            int gbase = (dqloc * 32 + n) * 5 * 8;
#pragma unroll
            for (int kg = 0; kg < 4; ++kg) {
                uint4 hh, ll;
                hh.x = pk2(hsv[8 * kg + 0], hsv[8 * kg + 1]);
                hh.y = pk2(hsv[8 * kg + 2], hsv[8 * kg + 3]);
                hh.z = pk2(hsv[8 * kg + 4], hsv[8 * kg + 5]);
                hh.w = pk2(hsv[8 * kg + 6], hsv[8 * kg + 7]);
                ll.x = pk2(lsv[8 * kg + 0], lsv[8 * kg + 1]);
                ll.y = pk2(lsv[8 * kg + 2], lsv[8 * kg + 3]);
                ll.z = pk2(lsv[8 * kg + 4], lsv[8 * kg + 5]);
                ll.w = pk2(lsv[8 * kg + 6], lsv[8 * kg + 7]);
                *(uint4*)&gh[gbase + kg * 8] = hh;
                *(uint4*)&gl[gbase + kg * 8] = ll;
            }
        }
        __syncthreads();
        for (int dqloc = 0; dqloc < 8; ++dqloc) {
            int dq = dq0 + dqloc;
            bf16x8 bh[2], bl[2];
#pragma unroll
            for (int nf = 0; nf < 2; ++nf) {
                int go = ((dqloc * 32 + nf * 16 + lr) * 5 + kg4) * 8;
                bh[nf] = *(bf16x8*)&gh[go];
                bl[nf] = *(bf16x8*)&gl[go];
            }
#pragma unroll
            for (int ffi = 0; ffi < 4; ++ffi) {
                int F = w + 4 * ffi;
                if (2 * F + 1 < dq) continue;
                int b = lr & 7, qoff = lr >> 3;
                int q = 2 * F + qoff;
                int j = 4 * (q - dq) + kg4 + 4;
                int xo = (b * 133 + j) * 8;
                bf16x8 ah = *(bf16x8*)&xh[xo];
                bf16x8 al = *(bf16x8*)&xl[xo];
#pragma unroll
                for (int nf = 0; nf < 2; ++nf) {
                    acc[ffi][nf] = __builtin_amdgcn_mfma_f32_16x16x32_bf16(ah, bh[nf], acc[ffi][nf], 0, 0, 0);
                    acc[ffi][nf] = __builtin_amdgcn_mfma_f32_16x16x32_bf16(al, bh[nf], acc[ffi][nf], 0, 0, 0);
                    acc[ffi][nf] = __builtin_amdgcn_mfma_f32_16x16x32_bf16(ah, bl[nf], acc[ffi][nf], 0, 0, 0);
                }
            }
        }
        __syncthreads();
    }

    float bsum[4] = {0, 0, 0, 0};
#pragma unroll
    for (int ffi = 0; ffi < 4; ++ffi) {
        int F = w + 4 * ffi;
#pragma unroll
        for (int nf = 0; nf < 2; ++nf) {
#pragma unroll
            for (int reg = 0; reg < 4; ++reg) {
                int mloc = 4 * kg4 + reg;
                int b = mloc & 7;
                int q = 2 * F + (mloc >> 3);
                int t = 32 * q + nf * 16 + lr;
                yT[((size_t)(b * 512 + c)) * 1024 + t] = acc[ffi][nf][reg];
                bsum[reg] += acc[ffi][nf][reg];
            }
        }
    }
#pragma unroll
    for (int off = 1; off < 16; off <<= 1) {
#pragma unroll
        for (int reg = 0; reg < 4; ++reg) bsum[reg] += __shfl_xor(bsum[reg], off, 64);
    }
    if (lr == 0) {
#pragma unroll
        for (int reg = 0; reg < 4; ++reg) ssh[w * 16 + kg4 * 4 + reg] = bsum[reg];
    }
    __syncthreads();
    if (tid < 8) {
        float tot = 0.0f;
        for (int w2 = 0; w2 < 4; ++w2) tot += ssh[w2 * 16 + tid] + ssh[w2 * 16 + 8 + tid];
        ssum[tid * 512 + c] = tot;
    }
}

__global__ __launch_bounds__(256) void se_kernel(const float* __restrict__ ssum,
                                                 const float* __restrict__ w1,
                                                 const float* __restrict__ b1,
                                                 const float* __restrict__ w2,
                                                 const float* __restrict__ b2,
                                                 float* __restrict__ g) {
    int b = blockIdx.x, tid = threadIdx.x;
    __shared__ float s_sh[512];
    __shared__ float part[256];
    __shared__ float h_sh[64];
    for (int c = tid; c < 512; c += 256) s_sh[c] = ssum[b * 512 + c] * (1.0f / 1024.0f);
    __syncthreads();
    int r = tid & 63, seg = tid >> 6;
    float p = 0.0f;
    for (int c = seg * 128; c < seg * 128 + 128; ++c) p += s_sh[c] * w1[r * 512 + c];
    part[tid] = p;
    __syncthreads();
    if (tid < 64) {
        float h = part[tid] + part[tid + 64] + part[tid + 128] + part[tid + 192] + b1[tid];
        h_sh[tid] = fmaxf(h, 0.0f);
    }
    __syncthreads();
    for (int c = tid; c < 512; c += 256) {
        float acc = b2[c];
#pragma unroll 8
        for (int rr = 0; rr < 64; ++rr) acc += h_sh[rr] * w2[c * 64 + rr];
        g[b * 512 + c] = 1.0f / (1.0f + expf(-acc));
    }
}

// ---------------------------------------------------------------------------
// fuse1t: merged transpose_y + fuse1 (unchanged).
// ---------------------------------------------------------------------------
__global__ __launch_bounds__(256) void fuse1t(const float* __restrict__ x,
                                              const float* __restrict__ yT,
                                              const float* __restrict__ g,
                                              const float* __restrict__ n1g,
                                              const float* __restrict__ n1b,
                                              unsigned short* __restrict__ y1b) {
    int ti = blockIdx.x, b = blockIdx.y, t0 = ti * 16, tid = threadIdx.x;
    __shared__ float tile[512 * 17];
    __shared__ float red1[256], red2[256];
    for (int i = tid; i < 2048; i += 256) {
        int c = i >> 2, tq = (i & 3) * 4;
        float4 v = *(const float4*)&yT[((size_t)(b * 512 + c)) * 1024 + t0 + tq];
        tile[c * 17 + tq + 0] = v.x;
        tile[c * 17 + tq + 1] = v.y;
        tile[c * 17 + tq + 2] = v.z;
        tile[c * 17 + tq + 3] = v.w;
    }
    __syncthreads();
    int tloc = tid >> 4, cg = tid & 15;
    int t = t0 + tloc;
    float vbuf[32];
    float s1 = 0.0f, s2 = 0.0f;
#pragma unroll
    for (int m = 0; m < 8; ++m) {
        int c = cg * 4 + 64 * m;
        float4 xv = *(const float4*)&x[((size_t)(b * 1024 + t)) * 512 + c];
        float4 gv = *(const float4*)&g[b * 512 + c];
        float v0 = xv.x + tile[(c + 0) * 17 + tloc] * gv.x;
        float v1 = xv.y + tile[(c + 1) * 17 + tloc] * gv.y;
        float v2 = xv.z + tile[(c + 2) * 17 + tloc] * gv.z;
        float v3 = xv.w + tile[(c + 3) * 17 + tloc] * gv.w;
        vbuf[m * 4 + 0] = v0; vbuf[m * 4 + 1] = v1;
        vbuf[m * 4 + 2] = v2; vbuf[m * 4 + 3] = v3;
        s1 += v0 + v1 + v2 + v3;
        s2 += v0 * v0 + v1 * v1 + v2 * v2 + v3 * v3;
    }
    red1[tid] = s1; red2[tid] = s2;
    __syncthreads();
    if (cg == 0) {
        float a1 = 0.0f, a2 = 0.0f;
#pragma unroll
        for (int k = 0; k < 16; ++k) { a1 += red1[tloc * 16 + k]; a2 += red2[tloc * 16 + k]; }
        red1[tloc * 16] = a1; red2[tloc * 16] = a2;
    }
    __syncthreads();
    float mean = red1[tloc * 16] * (1.0f / 512.0f);
    float var = red2[tloc * 16] * (1.0f / 512.0f) - mean * mean;
    float rstd = rsqrtf(var + 1e-5f);
#pragma unroll
    for (int m = 0; m < 8; ++m) {
        int c = cg * 4 + 64 * m;
        float4 g4 = *(const float4*)&n1g[c];
        float4 b4 = *(const float4*)&n1b[c];
        float o0 = (vbuf[m * 4 + 0] - mean) * rstd * g4.x + b4.x;
        float o1 = (vbuf[m * 4 + 1] - mean) * rstd * g4.y + b4.y;
        float o2 = (vbuf[m * 4 + 2] - mean) * rstd * g4.z + b4.z;
        float o3 = (vbuf[m * 4 + 3] - mean) * rstd * g4.w + b4.w;
        uint2 pk;
        pk.x = pk2(f2bf(o0), f2bf(o1));
        pk.y = pk2(f2bf(o2), f2bf(o3));
        *(uint2*)&y1b[((size_t)(b * 1024 + t)) * 512 + c] = pk;
    }
}

__device__ __forceinline__ int swz8(int slot, int row) { return slot ^ (row & 7); }

// ---------------------------------------------------------------------------
// GEMM1 + GLU: R12/R13 proven version — BM=64/BN=64, BK=64, 2-phase dbuf,
// gload_lds staging, XCD swizzle, fast-gelu.
// ---------------------------------------------------------------------------
__global__ __launch_bounds__(256) void gemm_glu(const unsigned short* __restrict__ A,
                                                const unsigned short* __restrict__ W,
                                                const float* __restrict__ bias,
                                                unsigned short* __restrict__ act) {
    const int K = 512;
    int id = blockIdx.x;
    int xcd = id & 7, local = id >> 3;
    int bx = 16 * xcd + (local & 15);
    int by = local >> 4;
    int m0 = bx * 64, n0 = by * 64;
    int tid = threadIdx.x, w = tid >> 6, l = tid & 63;
    __shared__ __align__(16) short As[2][4096];
    __shared__ __align__(16) short Bs[2][8192];
    const unsigned short* gA[2];
#pragma unroll
    for (int i = 0; i < 2; ++i) {
        int s = 2 * w + i;
        int row = 8 * s + (l >> 3);
        gA[i] = A + (size_t)(m0 + row) * K + (size_t)(((l & 7) ^ (row & 7)) * 8);
    }
    const unsigned short* gB[4];
#pragma unroll
    for (int i = 0; i < 4; ++i) {
        int s = 4 * w + i;
        int rb = 8 * s + (l >> 3);
        int grow = (rb < 64) ? (n0 + rb) : (1024 + n0 + rb - 64);
        gB[i] = W + (size_t)grow * K + (size_t)(((l & 7) ^ (rb & 7)) * 8);
    }
    int p = l >> 4, lr = l & 15;
    int arow = w * 16 + lr;
    f32x4 accA[4], accG[4];
#pragma unroll
    for (int ct = 0; ct < 4; ++ct) { accA[ct] = (f32x4)0.0f; accG[ct] = (f32x4)0.0f; }
#pragma unroll
    for (int i = 0; i < 2; ++i) gload16(gA[i], &As[0][(2 * w + i) * 512]);
#pragma unroll
    for (int i = 0; i < 4; ++i) gload16(gB[i], &Bs[0][(4 * w + i) * 512]);
    int cur = 0;
    for (int kt = 0; kt < K; kt += 64) {
        __syncthreads();
        if (kt + 64 < K) {
            int nb = cur ^ 1;
#pragma unroll
            for (int i = 0; i < 2; ++i) gload16(gA[i] + kt + 64, &As[nb][(2 * w + i) * 512]);
#pragma unroll
            for (int i = 0; i < 4; ++i) gload16(gB[i] + kt + 64, &Bs[nb][(4 * w + i) * 512]);
        }
#pragma unroll
        for (int ks = 0; ks < 2; ++ks) {
            int slot = ks * 4 + p;
            bf16x8 af = *(bf16x8*)&As[cur][arow * 64 + swz8(slot, arow) * 8];
            bf16x8 bA[4], bG[4];
#pragma unroll
            for (int ct = 0; ct < 4; ++ct) {
                int ca = ct * 16 + lr, cg = 64 + ct * 16 + lr;
                bA[ct] = *(bf16x8*)&Bs[cur][ca * 64 + swz8(slot, ca) * 8];
                bG[ct] = *(bf16x8*)&Bs[cur][cg * 64 + swz8(slot, cg) * 8];
            }
#pragma unroll
            for (int ct = 0; ct < 4; ++ct) {
                accA[ct] = __builtin_amdgcn_mfma_f32_16x16x32_bf16(af, bA[ct], accA[ct], 0, 0, 0);
                accG[ct] = __builtin_amdgcn_mfma_f32_16x16x32_bf16(af, bG[ct], accG[ct], 0, 0, 0);
            }
        }
        cur ^= 1;
    }
#pragma unroll
    for (int ct = 0; ct < 4; ++ct) {
        int col = n0 + ct * 16 + lr;
        float ba = bias[col], bg = bias[1024 + col];
#pragma unroll
        for (int reg = 0; reg < 4; ++reg) {
            int row = m0 + w * 16 + p * 4 + reg;
            float a = accA[ct][reg] + ba;
            float gg = accG[ct][reg] + bg;
            act[(size_t)row * 1024 + col] = f2bf(fast_gelu(a) * fast_sigmoid(gg));
        }
    }
}

// ---------------------------------------------------------------------------
// GEMM2: R12/R13 proven version, but output written as bf16 (halves zb
// write + fuse2 read traffic; ~4e-4 extra error vs 0.066 margin).
// ---------------------------------------------------------------------------
__global__ __launch_bounds__(256) void gemm_plain(const unsigned short* __restrict__ A,
                                                  const unsigned short* __restrict__ W,
                                                  const float* __restrict__ bias,
                                                  unsigned short* __restrict__ Cout) {
    const int K = 1024, N = 512;
    int id = blockIdx.x;
    int xcd = id & 7, local = id >> 3;
    int bx = 16 * xcd + (local & 15);
    int by = local >> 4;
    int m0 = bx * 64, n0 = by * 64;
    int tid = threadIdx.x, w = tid >> 6, l = tid & 63;
    int wr = w >> 1, wc = w & 1;
    __shared__ __align__(16) short As[2][4096];
    __shared__ __align__(16) short Bs[2][4096];
    const unsigned short* gA[2];
    const unsigned short* gB[2];
#pragma unroll
    for (int i = 0; i < 2; ++i) {
        int s = 2 * w + i;
        int row = 8 * s + (l >> 3);
        int koff = ((l & 7) ^ (row & 7)) * 8;
        gA[i] = A + (size_t)(m0 + row) * K + koff;
        gB[i] = W + (size_t)(n0 + row) * K + koff;
    }
    int p = l >> 4, lr = l & 15;
    f32x4 acc[2][2];
#pragma unroll
    for (int i = 0; i < 2; ++i)
#pragma unroll
        for (int j = 0; j < 2; ++j) acc[i][j] = (f32x4)0.0f;
#pragma unroll
    for (int i = 0; i < 2; ++i) {
        gload16(gA[i], &As[0][(2 * w + i) * 512]);
        gload16(gB[i], &Bs[0][(2 * w + i) * 512]);
    }
    int cur = 0;
    for (int kt = 0; kt < K; kt += 64) {
        __syncthreads();
        if (kt + 64 < K) {
            int nb = cur ^ 1;
#pragma unroll
            for (int i = 0; i < 2; ++i) {
                gload16(gA[i] + kt + 64, &As[nb][(2 * w + i) * 512]);
                gload16(gB[i] + kt + 64, &Bs[nb][(2 * w + i) * 512]);
            }
        }
#pragma unroll
        for (int ks = 0; ks < 2; ++ks) {
            int slot = ks * 4 + p;
            bf16x8 af[2], bfr[2];
#pragma unroll
            for (int t = 0; t < 2; ++t) {
                int r = wr * 32 + t * 16 + lr;
                af[t] = *(bf16x8*)&As[cur][r * 64 + swz8(slot, r) * 8];
                int cq = wc * 32 + t * 16 + lr;
                bfr[t] = *(bf16x8*)&Bs[cur][cq * 64 + swz8(slot, cq) * 8];
            }
#pragma unroll
            for (int i = 0; i < 2; ++i)
#pragma unroll
                for (int j = 0; j < 2; ++j)
                    acc[i][j] = __builtin_amdgcn_mfma_f32_16x16x32_bf16(af[i], bfr[j], acc[i][j], 0, 0, 0);
        }
        cur ^= 1;
    }
#pragma unroll
    for (int i = 0; i < 2; ++i)
#pragma unroll
        for (int j = 0; j < 2; ++j) {
            int col = n0 + wc * 32 + j * 16 + lr;
            float bb = bias[col];
#pragma unroll
            for (int reg = 0; reg < 4; ++reg) {
                int row = m0 + wr * 32 + i * 16 + p * 4 + reg;
                Cout[(size_t)row * N + col] = f2bf(acc[i][j][reg] + bb);
            }
        }
}

// fuse2: z2 = LN(y1+z, mixn); out = LN(y1+z2, n2). y1 and z read as bf16.
__global__ __launch_bounds__(128) void fuse2_kernel(const unsigned short* __restrict__ y1b,
                                                    const unsigned short* __restrict__ zbf,
                                                    const float* __restrict__ mg,
                                                    const float* __restrict__ mb,
                                                    const float* __restrict__ g2,
                                                    const float* __restrict__ b2v,
                                                    float* __restrict__ out) {
    int row = blockIdx.x, tid = threadIdx.x, c = tid * 4;
    __shared__ float r1[2], r2[2];
    uint2 yu = *(const uint2*)&y1b[(size_t)row * 512 + c];
    float4 a;
    a.x = __uint_as_float(yu.x << 16);
    a.y = __uint_as_float(yu.x & 0xffff0000u);
    a.z = __uint_as_float(yu.y << 16);
    a.w = __uint_as_float(yu.y & 0xffff0000u);
    uint2 zu = *(const uint2*)&zbf[(size_t)row * 512 + c];
    float4 zv;
    zv.x = __uint_as_float(zu.x << 16);
    zv.y = __uint_as_float(zu.x & 0xffff0000u);
    zv.z = __uint_as_float(zu.y << 16);
    zv.w = __uint_as_float(zu.y & 0xffff0000u);
    float4 t1;
    t1.x = a.x + zv.x; t1.y = a.y + zv.y; t1.z = a.z + zv.z; t1.w = a.w + zv.w;
    float s1 = t1.x + t1.y + t1.z + t1.w;
    float s2 = t1.x * t1.x + t1.y * t1.y + t1.z * t1.z + t1.w * t1.w;
#pragma unroll
    for (int off = 32; off > 0; off >>= 1) {
        s1 += __shfl_down(s1, off, 64);
        s2 += __shfl_down(s2, off, 64);
    }
    if ((tid & 63) == 0) { r1[tid >> 6] = s1; r2[tid >> 6] = s2; }
    __syncthreads();
    float mean = (r1[0] + r1[1]) * (1.0f / 512.0f);
    float var = (r2[0] + r2[1]) * (1.0f / 512.0f) - mean * mean;
    float rstd = rsqrtf(var + 1e-5f);
    float4 mg4 = *(const float4*)&mg[c];
    float4 mb4 = *(const float4*)&mb[c];
    float4 t2;
    t2.x = a.x + ((t1.x - mean) * rstd * mg4.x + mb4.x);
    t2.y = a.y + ((t1.y - mean) * rstd * mg4.y + mb4.y);
    t2.z = a.z + ((t1.z - mean) * rstd * mg4.z + mb4.z);
    t2.w = a.w + ((t1.w - mean) * rstd * mg4.w + mb4.w);
    __syncthreads();
    s1 = t2.x + t2.y + t2.z + t2.w;
    s2 = t2.x * t2.x + t2.y * t2.y + t2.z * t2.z + t2.w * t2.w;
#pragma unroll
    for (int off = 32; off > 0; off >>= 1) {
        s1 += __shfl_down(s1, off, 64);
        s2 += __shfl_down(s2, off, 64);
    }
    if ((tid & 63) == 0) { r1[tid >> 6] = s1; r2[tid >> 6] = s2; }
    __syncthreads();
    float mean2 = (r1[0] + r1[1]) * (1.0f / 512.0f);
    float var2 = (r2[0] + r2[1]) * (1.0f / 512.0f) - mean2 * mean2;
    float rstd2 = rsqrtf(var2 + 1e-5f);
    float4 gg = *(const float4*)&g2[c];
    float4 bb = *(const float4*)&b2v[c];
    float4 o;
    o.x = (t2.x - mean2) * rstd2 * gg.x + bb.x;
    o.y = (t2.y - mean2) * rstd2 * gg.y + bb.y;
    o.z = (t2.z - mean2) * rstd2 * gg.z + bb.z;
    o.w = (t2.w - mean2) * rstd2 * gg.w + bb.w;
    *(float4*)&out[(size_t)row * 512 + c] = o;
}

// ---------------------------------------------------------------------------
// Workspace layout (float offsets), same map as R13.
// ---------------------------------------------------------------------------
extern "C" void kernel_launch(void* const* d_in, const int* in_sizes, int n_in,
                              void* d_out, int out_size, void* d_ws, size_t ws_size,
                              hipStream_t stream) {
    (void)in_sizes; (void)n_in; (void)out_size; (void)ws_size;
    const float* x      = (const float*)d_in[0];
    const float* Bp     = (const float*)d_in[1];
    const float* Cp     = (const float*)d_in[2];
    const float* Dp     = (const float*)d_in[3];
    const float* log_dt = (const float*)d_in[4];
    const float* se_w1  = (const float*)d_in[5];
    const float* se_b1  = (const float*)d_in[6];
    const float* se_w2  = (const float*)d_in[7];
    const float* se_b2  = (const float*)d_in[8];
    const float* n1g    = (const float*)d_in[9];
    const float* n1b    = (const float*)d_in[10];
    const float* up_w   = (const float*)d_in[11];
    const float* up_b   = (const float*)d_in[12];
    const float* dn_w   = (const float*)d_in[13];
    const float* dn_b   = (const float*)d_in[14];
    const float* mxg    = (const float*)d_in[15];
    const float* mxb    = (const float*)d_in[16];
    const float* n2g    = (const float*)d_in[17];
    const float* n2b    = (const float*)d_in[18];

    float* ws = (float*)d_ws;
    float* Kr   = ws + 0;          //   524,288
    float* ssum = ws + 524352;     //     4,096
    float* gbuf = ws + 528448;     //     4,096
    unsigned short* up_wb = (unsigned short*)(ws + 532544);   // 524,288 fl
    unsigned short* dn_wb = (unsigned short*)(ws + 1056832);  // 262,144 fl
    float* Pow  = ws + 1450048;    //   163,840
    unsigned short* Bb_h = (unsigned short*)(ws + 1613888);   // 65,536 fl each
    unsigned short* Bb_l = (unsigned short*)(ws + 1679424);
    unsigned short* Cp_h = (unsigned short*)(ws + 1744960);
    unsigned short* Cp_l = (unsigned short*)(ws + 1810496);
    unsigned short* Pst_h = (unsigned short*)(ws + 1876032);  // 262,144 fl each
    unsigned short* Pst_l = (unsigned short*)(ws + 2138176);
    unsigned short* Qst_h = (unsigned short*)(ws + 2400320);
    unsigned short* Qst_l = (unsigned short*)(ws + 2662464);
    float* xT   = ws + 5021760;    //  4,194,304
    float* yT2  = ws + 9216064;    //  4,194,304
    unsigned short* zbf = (unsigned short*)(ws + 13410368);   //  262,144 fl as bf16
    unsigned short* act = (unsigned short*)(ws + 5021760);    // alias xT after conv
    unsigned short* y1b = (unsigned short*)(ws + 20971520);   // fresh region
    unsigned short* U_h2 = (unsigned short*)(ws + 25165824);
    unsigned short* U_l2 = (unsigned short*)(ws + 27262976);
    unsigned short* V_h2 = (unsigned short*)(ws + 29360128);
    unsigned short* V_l2 = (unsigned short*)(ws + 31457280);
    float* outp = (float*)d_out;

    hipLaunchKernelGGL(front_kernel, dim3(4940), dim3(256), 0, stream,
                       log_dt, Bp, up_w, dn_w, Cp, x,
                       Pow, Bb_h, Bb_l, up_wb, dn_wb, Cp_h, Cp_l, xT);
    hipLaunchKernelGGL(power_mats, dim3(64, 4), dim3(256), 0, stream, Pow, Pst_h, Pst_l, Qst_h, Qst_l);
    hipLaunchKernelGGL(kgemm_uv2, dim3(4, 32, 8), dim3(256), 0, stream,
                       Bb_h, Bb_l, Pst_h, Pst_l, Cp_h, Cp_l, Qst_h, Qst_l, V_h2, V_l2, U_h2, U_l2);
    hipLaunchKernelGGL(kgemm_kr, dim3(512), dim3(256), 0, stream, U_h2, U_l2, V_h2, V_l2, Dp, Kr);
    hipLaunchKernelGGL(conv_mfma, dim3(512), dim3(256), 0, stream, xT, Kr, yT2, ssum);
    hipLaunchKernelGGL(se_kernel, dim3(8), dim3(256), 0, stream, ssum, se_w1, se_b1, se_w2, se_b2, gbuf);
    hipLaunchKernelGGL(fuse1t, dim3(64, 8), dim3(256), 0, stream, x, yT2, gbuf, n1g, n1b, y1b);
    hipLaunchKernelGGL(gemm_glu, dim3(2048), dim3(256), 0, stream, y1b, up_wb, up_b, act);
    hipLaunchKernelGGL(gemm_plain, dim3(1024), dim3(256), 0, stream, act, dn_wb, dn_b, zbf);
    hipLaunchKernelGGL(fuse2_kernel, dim3(8192), dim3(128), 0, stream, y1b, zbf, mxg, mxb, n2g, n2b, outp);
}